// Round 7
// baseline (242.591 us; speedup 1.0000x reference)
//
#include <hip/hip_runtime.h>
#include <hip/hip_bf16.h>

// ---------------------------------------------------------------------------
// GCN 3-layer, N=50000, E=800000, D=64, fp32 in/out.
// R20: occupancy-ceiling lift on the gather kernels. R19 (row dbuf + traffic
// cut) was exactly null => gather is neither per-wave-latency nor HBM-BW
// bound; R14/R15 small gains say it has a concurrency-sensitive component.
// At launch_bounds(256,4), 1564 blocks ran as 1024 resident + 540-block tail
// at 53% occupancy. The R15-form gather body fits 60 VGPR (measured on the
// R18 mega kernel) — under the 64-VGPR doubling threshold. This round:
// __launch_bounds__(256,8) (VGPR<=64 -> 8 blocks/CU) on aggemm/agg/fill, all
// 1564 blocks co-resident (+53% avg concurrency, no tail round). Gather
// reverted to R15 prefetch form (row-dbuf null anyway; frees ~32 VGPR to fit
// the cap). Keep R19's bf16 h1 + LDS-staged coalesced stores (traffic cut,
// neutral time). Accounting note: dur_us includes the 44us harness ws-poison
// fill (182 - 44 = 138 ~= kernel-sum); optimizable pipeline ~138us.
// R15: index prefetch, stage_W after Phase A, dinv via LDS. R14: 32
// nodes/block. R13: agg+gemm fusion through LDS. R8/R12 gather floor form,
// XCD-partitioned fill (R3/R4), bf16 table (R6), MFMA 16x16x32 gemm (R8).
// ---------------------------------------------------------------------------

#define CAP 64
#define EDGE_CHUNK 1024

typedef __attribute__((ext_vector_type(8))) short bf16x8;
typedef __attribute__((ext_vector_type(4))) float f32x4;

// --- pack two fp32 -> bf16x2 (RNE) ----------------------------------------
__device__ inline unsigned pack_bf16(float a, float b) {
    union { float f; unsigned i; } ua, ub;
    ua.f = a; ub.f = b;
    unsigned x = (ua.i + 0x7fffu + ((ua.i >> 16) & 1u)) >> 16;
    unsigned y = (ub.i + 0x7fffu + ((ub.i >> 16) & 1u)) >> 16;
    return x | (y << 16);
}
__device__ inline unsigned short to_bf16(float a) {
    union { float f; unsigned i; } u; u.f = a;
    return (unsigned short)((u.i + 0x7fffu + ((u.i >> 16) & 1u)) >> 16);
}
// --- accumulate bf16x2 (packed uint) into two floats ----------------------
__device__ inline void acc_bf16x2(unsigned u, float& a, float& b) {
    union { unsigned i; float f; } lo, hi;
    lo.i = u << 16;
    hi.i = u & 0xffff0000u;
    a += lo.f; b += hi.f;
}

// --- 8-lane/node uint4 row gather with index prefetch (R15 form) ----------
__device__ inline void gather_rows(const unsigned short* __restrict__ g,
                                   const int* __restrict__ lst, int deg, int c8,
                                   float& a0, float& a1, float& a2, float& a3,
                                   float& a4, float& a5, float& a6, float& a7) {
    int nfull = deg >> 3;              // full 8-batches
    int4 ja, jb;
    if (nfull > 0) { ja = *(const int4*)&lst[0]; jb = *(const int4*)&lst[4]; }
    for (int b = 0; b < nfull; b++) {
        int4 na = ja, nb = jb;         // prefetch next batch's indices
        if (b + 1 < nfull) {
            na = *(const int4*)&lst[(b + 1) * 8];
            nb = *(const int4*)&lst[(b + 1) * 8 + 4];
        }
        uint4 w0 = *(const uint4*)&g[(size_t)ja.x * 64 + c8];
        uint4 w1 = *(const uint4*)&g[(size_t)ja.y * 64 + c8];
        uint4 w2 = *(const uint4*)&g[(size_t)ja.z * 64 + c8];
        uint4 w3 = *(const uint4*)&g[(size_t)ja.w * 64 + c8];
        uint4 w4 = *(const uint4*)&g[(size_t)jb.x * 64 + c8];
        uint4 w5 = *(const uint4*)&g[(size_t)jb.y * 64 + c8];
        uint4 w6 = *(const uint4*)&g[(size_t)jb.z * 64 + c8];
        uint4 w7 = *(const uint4*)&g[(size_t)jb.w * 64 + c8];
        acc_bf16x2(w0.x, a0, a1); acc_bf16x2(w0.y, a2, a3);
        acc_bf16x2(w0.z, a4, a5); acc_bf16x2(w0.w, a6, a7);
        acc_bf16x2(w1.x, a0, a1); acc_bf16x2(w1.y, a2, a3);
        acc_bf16x2(w1.z, a4, a5); acc_bf16x2(w1.w, a6, a7);
        acc_bf16x2(w2.x, a0, a1); acc_bf16x2(w2.y, a2, a3);
        acc_bf16x2(w2.z, a4, a5); acc_bf16x2(w2.w, a6, a7);
        acc_bf16x2(w3.x, a0, a1); acc_bf16x2(w3.y, a2, a3);
        acc_bf16x2(w3.z, a4, a5); acc_bf16x2(w3.w, a6, a7);
        acc_bf16x2(w4.x, a0, a1); acc_bf16x2(w4.y, a2, a3);
        acc_bf16x2(w4.z, a4, a5); acc_bf16x2(w4.w, a6, a7);
        acc_bf16x2(w5.x, a0, a1); acc_bf16x2(w5.y, a2, a3);
        acc_bf16x2(w5.z, a4, a5); acc_bf16x2(w5.w, a6, a7);
        acc_bf16x2(w6.x, a0, a1); acc_bf16x2(w6.y, a2, a3);
        acc_bf16x2(w6.z, a4, a5); acc_bf16x2(w6.w, a6, a7);
        acc_bf16x2(w7.x, a0, a1); acc_bf16x2(w7.y, a2, a3);
        acc_bf16x2(w7.z, a4, a5); acc_bf16x2(w7.w, a6, a7);
        ja = na; jb = nb;
    }
    int k = nfull * 8;
    if (k + 4 <= deg) {
        int4 j4 = *(const int4*)&lst[k];
        uint4 w0 = *(const uint4*)&g[(size_t)j4.x * 64 + c8];
        uint4 w1 = *(const uint4*)&g[(size_t)j4.y * 64 + c8];
        uint4 w2 = *(const uint4*)&g[(size_t)j4.z * 64 + c8];
        uint4 w3 = *(const uint4*)&g[(size_t)j4.w * 64 + c8];
        acc_bf16x2(w0.x, a0, a1); acc_bf16x2(w0.y, a2, a3);
        acc_bf16x2(w0.z, a4, a5); acc_bf16x2(w0.w, a6, a7);
        acc_bf16x2(w1.x, a0, a1); acc_bf16x2(w1.y, a2, a3);
        acc_bf16x2(w1.z, a4, a5); acc_bf16x2(w1.w, a6, a7);
        acc_bf16x2(w2.x, a0, a1); acc_bf16x2(w2.y, a2, a3);
        acc_bf16x2(w2.z, a4, a5); acc_bf16x2(w2.w, a6, a7);
        acc_bf16x2(w3.x, a0, a1); acc_bf16x2(w3.y, a2, a3);
        acc_bf16x2(w3.z, a4, a5); acc_bf16x2(w3.w, a6, a7);
        k += 4;
    }
    for (; k < deg; k++) {
        uint4 v = *(const uint4*)&g[(size_t)lst[k] * 64 + c8];
        acc_bf16x2(v.x, a0, a1); acc_bf16x2(v.y, a2, a3);
        acc_bf16x2(v.z, a4, a5); acc_bf16x2(v.w, a6, a7);
    }
}

// --- fused count+place: slot = atomicAdd(cnt), XCD-partitioned by dst -----
__global__ __launch_bounds__(256, 8) void fill_kernel(
        const int* __restrict__ src, const int* __restrict__ dst,
        int* __restrict__ cnt, int* __restrict__ adj,
        int E, int npc) {
    int cls = blockIdx.x & 7;          // -> XCD (round-robin heuristic)
    int base = (blockIdx.x >> 3) * EDGE_CHUNK;
    int end = min(base + EDGE_CHUNK, E);
    int lo = cls * npc, hi = lo + npc;
    for (int e = base + threadIdx.x; e < end; e += blockDim.x) {
        int d = dst[e];
        if (d >= lo && d < hi) {
            int p = atomicAdd(&cnt[d], 1);
            adj[(size_t)d * CAP + p] = src[e];
        }
    }
}

// --- stage W (fp32 64x64) into B-fragment order (bf16) in LDS -------------
__device__ inline void stage_W(const float* __restrict__ W, unsigned short* Wb, int t) {
#pragma unroll
    for (int e0 = 0; e0 < 2; e0++) {
        int e = t + e0 * 256;          // frag index 0..511
        int sc = e >> 6;               // s*4 + c
        int l  = e & 63;               // target lane
        int s = sc >> 2, c = sc & 3;
        int nn = c * 16 + (l & 15);
        int kb = s * 32 + (l >> 4) * 8;
        const float* wp = &W[(size_t)kb * 64 + nn];
        unsigned q0 = pack_bf16(wp[0 * 64], wp[1 * 64]);
        unsigned q1 = pack_bf16(wp[2 * 64], wp[3 * 64]);
        unsigned q2 = pack_bf16(wp[4 * 64], wp[5 * 64]);
        unsigned q3 = pack_bf16(wp[6 * 64], wp[7 * 64]);
        *(uint4*)&Wb[e * 8] = make_uint4(q0, q1, q2, q3);
    }
}

// --- g(bf16) = dinv ⊙ (in @ W) via MFMA; 64 rows/block (layer 1 only) -----
// Output staged through Wb-as-Ofrag (free after MFMA) for coalesced stores.
__global__ __launch_bounds__(256, 4) void gemm_kernel(const float* __restrict__ in,
                                                      const float* __restrict__ W,
                                                      const int* __restrict__ cnt,
                                                      unsigned short* __restrict__ g, int n) {
    __shared__ unsigned short Wb[512 * 8];     // B-frags, then out-tile alias
    int t = threadIdx.x;
    stage_W(W, Wb, t);

    int wv = t >> 6;
    int lane = t & 63;
    int quad = lane >> 4;
    int m16 = lane & 15;

    int rowA = blockIdx.x * 64 + wv * 16 + m16;
    union { bf16x8 v; uint4 u; } a0, a1;
    {
        float4 f0 = make_float4(0, 0, 0, 0), f1 = f0, f2 = f0, f3 = f0;
        if (rowA < n) {
            const float* rp = &in[(size_t)rowA * 64];
            f0 = *(const float4*)&rp[quad * 8];
            f1 = *(const float4*)&rp[quad * 8 + 4];
            f2 = *(const float4*)&rp[32 + quad * 8];
            f3 = *(const float4*)&rp[32 + quad * 8 + 4];
        }
        a0.u = make_uint4(pack_bf16(f0.x, f0.y), pack_bf16(f0.z, f0.w),
                          pack_bf16(f1.x, f1.y), pack_bf16(f1.z, f1.w));
        a1.u = make_uint4(pack_bf16(f2.x, f2.y), pack_bf16(f2.z, f2.w),
                          pack_bf16(f3.x, f3.y), pack_bf16(f3.z, f3.w));
    }
    __syncthreads();

    f32x4 acc[4];
#pragma unroll
    for (int c = 0; c < 4; c++) {
        bf16x8 b0 = *(const bf16x8*)&Wb[((size_t)(0 * 4 + c) * 64 + lane) * 8];
        bf16x8 b1 = *(const bf16x8*)&Wb[((size_t)(1 * 4 + c) * 64 + lane) * 8];
        f32x4 z = {0.f, 0.f, 0.f, 0.f};
        z = __builtin_amdgcn_mfma_f32_16x16x32_bf16(a0.v, b0, z, 0, 0, 0);
        z = __builtin_amdgcn_mfma_f32_16x16x32_bf16(a1.v, b1, z, 0, 0, 0);
        acc[c] = z;
    }

    int lrow = wv * 16 + quad * 4;            // local row base 0..63
    float dv[4];
#pragma unroll
    for (int r = 0; r < 4; r++) {
        int row = blockIdx.x * 64 + lrow + r;
        dv[r] = (row < n) ? rsqrtf((float)(cnt[row] + 1)) : 0.f;
    }
    __syncthreads();                          // Wb B-frag reads all done
    unsigned short* Ofrag = Wb;               // 64x64 ushort = 8KB alias
#pragma unroll
    for (int c = 0; c < 4; c++) {
#pragma unroll
        for (int r = 0; r < 4; r++)
            Ofrag[(size_t)(lrow + r) * 64 + c * 16 + m16] = to_bf16(acc[c][r] * dv[r]);
    }
    __syncthreads();
#pragma unroll
    for (int it = 0; it < 2; it++) {
        int unit = t + it * 256;              // 512 units: 64 rows x 8 chunks
        int row = unit >> 3, chv = unit & 7;
        int grow = blockIdx.x * 64 + row;
        if (grow < n)
            *(uint4*)&g[(size_t)grow * 64 + chv * 8] =
                *(const uint4*)&Ofrag[(size_t)row * 64 + chv * 8];
    }
}

// --- fused agg(l) + gemm(l+1); 32 nodes/block; 8 blocks/CU (R20) ----------
// Phase A: R15 uint4 gather (8 lanes/node, index prefetch); h =
// relu(dinv*sum+bias)+res; h written bf16 (WRITE_H); deposit h into A-frag
// LDS + dinv into LDS. Phase B: MFMA, out-tile staged back into Afrag for
// coalesced stores. launch_bounds(256,8): VGPR<=64 -> all 1564 blocks
// co-resident (no tail round).
template <int WRITE_H, int RES_BF16>
__global__ __launch_bounds__(256, 8) void aggemm_kernel(
        const unsigned short* __restrict__ g_in,
        const int* __restrict__ cnt,
        const int* __restrict__ adj,
        const float* __restrict__ bias,
        const void* __restrict__ res_p,
        const float* __restrict__ W,
        unsigned short* __restrict__ h_out,   // bf16 h (if WRITE_H)
        unsigned short* __restrict__ g_out,
        int n) {
    __shared__ unsigned short Wb[512 * 8];     // 8 KB B-frags
    __shared__ unsigned short Afrag[2048];     // 4 KB A-frags, then out-tile
    __shared__ float dsh[32];                  // per-node dinv for Phase B
    int t = threadIdx.x;

    // ---- Phase A: aggregate 32 nodes, 8 lanes/node, uint4 ----
    int r  = t >> 3;                   // node-in-block 0..31
    int lg = t & 7;
    const int c8 = lg * 8;
    int i = blockIdx.x * 32 + r;
    float v0 = 0.f, v1 = 0.f, v2 = 0.f, v3 = 0.f;
    float v4 = 0.f, v5 = 0.f, v6 = 0.f, v7 = 0.f;
    float dvv = 0.f;
    if (i < n) {
        int deg = cnt[i];
        const int* lst = adj + (size_t)i * CAP;
        float r0 = 0.f, r1 = 0.f, r2 = 0.f, r3 = 0.f;
        float r4 = 0.f, r5 = 0.f, r6 = 0.f, r7 = 0.f;
        if (RES_BF16) {                // hoisted residual load (bf16 h1)
            const unsigned short* rp = (const unsigned short*)res_p;
            uint4 rv = *(const uint4*)&rp[(size_t)i * 64 + c8];
            acc_bf16x2(rv.x, r0, r1); acc_bf16x2(rv.y, r2, r3);
            acc_bf16x2(rv.z, r4, r5); acc_bf16x2(rv.w, r6, r7);
        } else {                       // fp32 residual (x)
            const float* rp = (const float*)res_p;
            float4 q0 = *(const float4*)&rp[(size_t)i * 64 + c8];
            float4 q1 = *(const float4*)&rp[(size_t)i * 64 + c8 + 4];
            r0 = q0.x; r1 = q0.y; r2 = q0.z; r3 = q0.w;
            r4 = q1.x; r5 = q1.y; r6 = q1.z; r7 = q1.w;
        }
        float a0 = 0.f, a1 = 0.f, a2 = 0.f, a3 = 0.f;
        float a4 = 0.f, a5 = 0.f, a6 = 0.f, a7 = 0.f;
        {   // self loop
            uint4 v = *(const uint4*)&g_in[(size_t)i * 64 + c8];
            acc_bf16x2(v.x, a0, a1); acc_bf16x2(v.y, a2, a3);
            acc_bf16x2(v.z, a4, a5); acc_bf16x2(v.w, a6, a7);
        }
        gather_rows(g_in, lst, deg, c8, a0, a1, a2, a3, a4, a5, a6, a7);
        dvv = rsqrtf((float)(deg + 1));
        float4 b0 = *(const float4*)&bias[c8];
        float4 b1 = *(const float4*)&bias[c8 + 4];
        v0 = fmaxf(dvv * a0 + b0.x, 0.f) + r0;
        v1 = fmaxf(dvv * a1 + b0.y, 0.f) + r1;
        v2 = fmaxf(dvv * a2 + b0.z, 0.f) + r2;
        v3 = fmaxf(dvv * a3 + b0.w, 0.f) + r3;
        v4 = fmaxf(dvv * a4 + b1.x, 0.f) + r4;
        v5 = fmaxf(dvv * a5 + b1.y, 0.f) + r5;
        v6 = fmaxf(dvv * a6 + b1.z, 0.f) + r6;
        v7 = fmaxf(dvv * a7 + b1.w, 0.f) + r7;
    }
    // pack h row chunk once: reused for h_out write and A-frag deposit
    uint4 pk;
    pk.x = pack_bf16(v0, v1);
    pk.y = pack_bf16(v2, v3);
    pk.z = pack_bf16(v4, v5);
    pk.w = pack_bf16(v6, v7);
    if (WRITE_H && i < n)
        *(uint4*)&h_out[(size_t)i * 64 + c8] = pk;
    // stage W after the gather (R15): latency hides under other waves' A.
    stage_W(W, Wb, t);
    {
        int sA = r >> 4, mA = r & 15;
        *(uint4*)&Afrag[((size_t)(sA * 8 + lg) * 16 + mA) * 8] = pk;
        if (lg == 0) dsh[r] = dvv;
    }
    __syncthreads();

    // ---- Phase B: MFMA gemm on the 32-row tile ----
    int wv = t >> 6;
    int lane = t & 63;
    int quad = lane >> 4;
    int m16 = lane & 15;
    int sB = wv & 1;                   // row sub-tile 0..1
    int ch = wv >> 1;                  // col half 0..1
    bf16x8 af0 = *(const bf16x8*)&Afrag[((size_t)(sB * 8 + quad) * 16 + m16) * 8];
    bf16x8 af1 = *(const bf16x8*)&Afrag[((size_t)(sB * 8 + 4 + quad) * 16 + m16) * 8];
    int lrow = sB * 16 + quad * 4;     // local row 0..31
    float dv2[4];
#pragma unroll
    for (int rr = 0; rr < 4; rr++)
        dv2[rr] = dsh[lrow + rr];
    __syncthreads();                   // all A-frag reads done before overwrite
    f32x4 acc[2];
#pragma unroll
    for (int c2 = 0; c2 < 2; c2++) {
        int c = ch * 2 + c2;
        bf16x8 b0 = *(const bf16x8*)&Wb[((size_t)(0 * 4 + c) * 64 + lane) * 8];
        bf16x8 b1 = *(const bf16x8*)&Wb[((size_t)(1 * 4 + c) * 64 + lane) * 8];
        f32x4 z = {0.f, 0.f, 0.f, 0.f};
        z = __builtin_amdgcn_mfma_f32_16x16x32_bf16(af0, b0, z, 0, 0, 0);
        z = __builtin_amdgcn_mfma_f32_16x16x32_bf16(af1, b1, z, 0, 0, 0);
        acc[c2] = z;
    }
    // stage out-tile into Afrag [32][64] for coalesced stores
#pragma unroll
    for (int c2 = 0; c2 < 2; c2++) {
        int c = ch * 2 + c2;
#pragma unroll
        for (int rr = 0; rr < 4; rr++)
            Afrag[(size_t)(lrow + rr) * 64 + c * 16 + m16] = to_bf16(acc[c2][rr] * dv2[rr]);
    }
    __syncthreads();
    {
        int orow = blockIdx.x * 32 + r;
        if (orow < n)
            *(uint4*)&g_out[(size_t)orow * 64 + c8] =
                *(const uint4*)&Afrag[(size_t)r * 64 + c8];
    }
}

// --- final aggregation: 8 lanes/node uint4; 8 blocks/CU (R20) -------------
__global__ __launch_bounds__(256, 8) void agg_kernel(const unsigned short* __restrict__ g,
                                                     const int* __restrict__ cnt,
                                                     const int* __restrict__ adj,
                                                     const float* __restrict__ bias,
                                                     float* __restrict__ out, int n) {
    int t = threadIdx.x;
    int lg = t & 7;
    int i = blockIdx.x * 32 + (t >> 3);
    if (i >= n) return;
    int deg = cnt[i];
    const int* lst = adj + (size_t)i * CAP;
    const int c8 = lg * 8;
    size_t rowoff = (size_t)i * 64 + c8;
    float a0 = 0.f, a1 = 0.f, a2 = 0.f, a3 = 0.f;
    float a4 = 0.f, a5 = 0.f, a6 = 0.f, a7 = 0.f;
    {   // self loop
        uint4 v = *(const uint4*)&g[(size_t)i * 64 + c8];
        acc_bf16x2(v.x, a0, a1); acc_bf16x2(v.y, a2, a3);
        acc_bf16x2(v.z, a4, a5); acc_bf16x2(v.w, a6, a7);
    }
    gather_rows(g, lst, deg, c8, a0, a1, a2, a3, a4, a5, a6, a7);
    float dv = rsqrtf((float)(deg + 1));
    float4 b0 = *(const float4*)&bias[c8];
    float4 b1 = *(const float4*)&bias[c8 + 4];
    float4 o0, o1;
    o0.x = dv * a0 + b0.x; o0.y = dv * a1 + b0.y;
    o0.z = dv * a2 + b0.z; o0.w = dv * a3 + b0.w;
    o1.x = dv * a4 + b1.x; o1.y = dv * a5 + b1.y;
    o1.z = dv * a6 + b1.z; o1.w = dv * a7 + b1.w;
    *(float4*)&out[rowoff] = o0;
    *(float4*)&out[rowoff + 4] = o1;
}

extern "C" void kernel_launch(void* const* d_in, const int* in_sizes, int n_in,
                              void* d_out, int out_size, void* d_ws, size_t ws_size,
                              hipStream_t stream) {
    const float* x  = (const float*)d_in[0];
    const int*   ei = (const int*)d_in[1];
    const float* W1 = (const float*)d_in[2];
    const float* b1 = (const float*)d_in[3];
    const float* W2 = (const float*)d_in[4];
    const float* b2 = (const float*)d_in[5];
    const float* W3 = (const float*)d_in[6];
    const float* b3 = (const float*)d_in[7];
    float* out = (float*)d_out;

    const int N = in_sizes[0] / 64;
    const int E = in_sizes[1] / 2;
    const int* src = ei;
    const int* dst = ei + E;
    const int npc = (N + 7) / 8;
    const int nEdgeChunks = (E + EDGE_CHUNK - 1) / EDGE_CHUNK;

    // workspace layout
    char* p = (char*)d_ws;
    const int Na = ((N + 63) / 64) * 64;
    int*            cnt = (int*)p;            p += (size_t)Na * 4;
    int*            adj = (int*)p;            p += ((size_t)N + 1) * CAP * 4;
    unsigned short* ga  = (unsigned short*)p; p += (size_t)N * 64 * 2;
    unsigned short* gb  = (unsigned short*)p; p += (size_t)N * 64 * 2;
    unsigned short* h1  = (unsigned short*)p; p += (size_t)N * 64 * 2;   // bf16

    const int tileBlocks = (N + 63) / 64;   // gemm (64-row MFMA tiles)
    const int halfBlocks = (N + 31) / 32;   // aggemm + final agg (32 nodes)

    // --- bucket adjacency build (ws re-poisoned every call) ---
    hipMemsetAsync(cnt, 0, (size_t)N * 4, stream);
    fill_kernel<<<nEdgeChunks * 8, 256, 0, stream>>>(src, dst, cnt, adj, E, npc);

    // --- layer 1 gemm: ga = dinv ⊙ (x@W1) ---
    gemm_kernel<<<tileBlocks, 256, 0, stream>>>(x, W1, cnt, ga, N);
    // --- fused: h1 = relu(agg(ga))+x (bf16) ; gb = dinv ⊙ (h1@W2) ---
    aggemm_kernel<1, 0><<<halfBlocks, 256, 0, stream>>>(ga, cnt, adj, b1, (const void*)x,
                                                        W2, h1, gb, N);
    // --- fused: h2 = relu(agg(gb))+h1 ; ga = dinv ⊙ (h2@W3) ---
    aggemm_kernel<0, 1><<<halfBlocks, 256, 0, stream>>>(gb, cnt, adj, b2, (const void*)h1,
                                                        W3, nullptr, ga, N);
    // --- final: out = agg(ga) + b3 ---
    agg_kernel<<<halfBlocks, 256, 0, stream>>>(ga, cnt, adj, b3, out, N);
}

// Round 8
// 209.910 us; speedup vs baseline: 1.1557x; 1.1557x over previous
//
#include <hip/hip_runtime.h>
#include <hip/hip_bf16.h>

// ---------------------------------------------------------------------------
// GCN 3-layer, N=50000, E=800000, D=64, fp32 in/out.
// R21: planar feature-split gather. R20's counters (first real visibility):
// agg FETCH=84.5MB for a 6.4MB table at 3.58TB/s, VALU 9%, Mfma 0 — the
// gather is pinned at a random-access HBM wall fed by (a) 8 XCDs each
// pulling a private copy (~51MB compulsory) and (b) intra-XCD capacity
// thrash (6.4MB table vs 4MB L2). Fix: split g into two PLANES gLo[N][32] /
// gHi[N][32] (3.2MB each, L2-capacity-resident); gather = two block-level
// passes over the same adjacency (lanes 0-3 sum cols 0-31 from gLo;
// __syncthreads(); lanes 4-7 sum cols 32-63 from gHi). Same request count &
// bytes, same per-feature accumulation order (absmax unchanged); barrier
// both aligns the chip-wide window and stops the compiler merging the
// complementary-mask passes. Writers emit planar layout via the existing
// LDS-staged coalesced stores. R20's (256,8) REVERTED (it forced VGPR=32,
// killing gather MLP: agg 28->45us). Keep R19's bf16 h1 + staged stores.
// R15: index prefetch, stage_W after gather, dinv via LDS. R14: 32
// nodes/block. R13: agg+gemm fusion. R3/R4 XCD fill, R6 bf16 table, R8 MFMA.
// ---------------------------------------------------------------------------

#define CAP 64
#define EDGE_CHUNK 1024

typedef __attribute__((ext_vector_type(8))) short bf16x8;
typedef __attribute__((ext_vector_type(4))) float f32x4;

// --- pack two fp32 -> bf16x2 (RNE) ----------------------------------------
__device__ inline unsigned pack_bf16(float a, float b) {
    union { float f; unsigned i; } ua, ub;
    ua.f = a; ub.f = b;
    unsigned x = (ua.i + 0x7fffu + ((ua.i >> 16) & 1u)) >> 16;
    unsigned y = (ub.i + 0x7fffu + ((ub.i >> 16) & 1u)) >> 16;
    return x | (y << 16);
}
__device__ inline unsigned short to_bf16(float a) {
    union { float f; unsigned i; } u; u.f = a;
    return (unsigned short)((u.i + 0x7fffu + ((u.i >> 16) & 1u)) >> 16);
}
// --- accumulate bf16x2 (packed uint) into two floats ----------------------
__device__ inline void acc_bf16x2(unsigned u, float& a, float& b) {
    union { unsigned i; float f; } lo, hi;
    lo.i = u << 16;
    hi.i = u & 0xffff0000u;
    a += lo.f; b += hi.f;
}

// --- planar row gather: rows of 32 bf16 (64B); lane reads 16B at off ------
// Index prefetch one batch ahead (R15 form). Called under a half-lane mask.
__device__ inline void gather_plane(const unsigned short* __restrict__ gp,
                                    const int* __restrict__ lst, int deg, int off,
                                    float& a0, float& a1, float& a2, float& a3,
                                    float& a4, float& a5, float& a6, float& a7) {
    int nfull = deg >> 3;              // full 8-batches
    int4 ja, jb;
    if (nfull > 0) { ja = *(const int4*)&lst[0]; jb = *(const int4*)&lst[4]; }
    for (int b = 0; b < nfull; b++) {
        int4 na = ja, nb = jb;         // prefetch next batch's indices
        if (b + 1 < nfull) {
            na = *(const int4*)&lst[(b + 1) * 8];
            nb = *(const int4*)&lst[(b + 1) * 8 + 4];
        }
        uint4 w0 = *(const uint4*)&gp[(size_t)ja.x * 32 + off];
        uint4 w1 = *(const uint4*)&gp[(size_t)ja.y * 32 + off];
        uint4 w2 = *(const uint4*)&gp[(size_t)ja.z * 32 + off];
        uint4 w3 = *(const uint4*)&gp[(size_t)ja.w * 32 + off];
        uint4 w4 = *(const uint4*)&gp[(size_t)jb.x * 32 + off];
        uint4 w5 = *(const uint4*)&gp[(size_t)jb.y * 32 + off];
        uint4 w6 = *(const uint4*)&gp[(size_t)jb.z * 32 + off];
        uint4 w7 = *(const uint4*)&gp[(size_t)jb.w * 32 + off];
        acc_bf16x2(w0.x, a0, a1); acc_bf16x2(w0.y, a2, a3);
        acc_bf16x2(w0.z, a4, a5); acc_bf16x2(w0.w, a6, a7);
        acc_bf16x2(w1.x, a0, a1); acc_bf16x2(w1.y, a2, a3);
        acc_bf16x2(w1.z, a4, a5); acc_bf16x2(w1.w, a6, a7);
        acc_bf16x2(w2.x, a0, a1); acc_bf16x2(w2.y, a2, a3);
        acc_bf16x2(w2.z, a4, a5); acc_bf16x2(w2.w, a6, a7);
        acc_bf16x2(w3.x, a0, a1); acc_bf16x2(w3.y, a2, a3);
        acc_bf16x2(w3.z, a4, a5); acc_bf16x2(w3.w, a6, a7);
        acc_bf16x2(w4.x, a0, a1); acc_bf16x2(w4.y, a2, a3);
        acc_bf16x2(w4.z, a4, a5); acc_bf16x2(w4.w, a6, a7);
        acc_bf16x2(w5.x, a0, a1); acc_bf16x2(w5.y, a2, a3);
        acc_bf16x2(w5.z, a4, a5); acc_bf16x2(w5.w, a6, a7);
        acc_bf16x2(w6.x, a0, a1); acc_bf16x2(w6.y, a2, a3);
        acc_bf16x2(w6.z, a4, a5); acc_bf16x2(w6.w, a6, a7);
        acc_bf16x2(w7.x, a0, a1); acc_bf16x2(w7.y, a2, a3);
        acc_bf16x2(w7.z, a4, a5); acc_bf16x2(w7.w, a6, a7);
        ja = na; jb = nb;
    }
    int k = nfull * 8;
    if (k + 4 <= deg) {
        int4 j4 = *(const int4*)&lst[k];
        uint4 w0 = *(const uint4*)&gp[(size_t)j4.x * 32 + off];
        uint4 w1 = *(const uint4*)&gp[(size_t)j4.y * 32 + off];
        uint4 w2 = *(const uint4*)&gp[(size_t)j4.z * 32 + off];
        uint4 w3 = *(const uint4*)&gp[(size_t)j4.w * 32 + off];
        acc_bf16x2(w0.x, a0, a1); acc_bf16x2(w0.y, a2, a3);
        acc_bf16x2(w0.z, a4, a5); acc_bf16x2(w0.w, a6, a7);
        acc_bf16x2(w1.x, a0, a1); acc_bf16x2(w1.y, a2, a3);
        acc_bf16x2(w1.z, a4, a5); acc_bf16x2(w1.w, a6, a7);
        acc_bf16x2(w2.x, a0, a1); acc_bf16x2(w2.y, a2, a3);
        acc_bf16x2(w2.z, a4, a5); acc_bf16x2(w2.w, a6, a7);
        acc_bf16x2(w3.x, a0, a1); acc_bf16x2(w3.y, a2, a3);
        acc_bf16x2(w3.z, a4, a5); acc_bf16x2(w3.w, a6, a7);
        k += 4;
    }
    for (; k < deg; k++) {
        uint4 v = *(const uint4*)&gp[(size_t)lst[k] * 32 + off];
        acc_bf16x2(v.x, a0, a1); acc_bf16x2(v.y, a2, a3);
        acc_bf16x2(v.z, a4, a5); acc_bf16x2(v.w, a6, a7);
    }
}

// --- fused count+place: slot = atomicAdd(cnt), XCD-partitioned by dst -----
__global__ void fill_kernel(const int* __restrict__ src, const int* __restrict__ dst,
                            int* __restrict__ cnt, int* __restrict__ adj,
                            int E, int npc) {
    int cls = blockIdx.x & 7;          // -> XCD (round-robin heuristic)
    int base = (blockIdx.x >> 3) * EDGE_CHUNK;
    int end = min(base + EDGE_CHUNK, E);
    int lo = cls * npc, hi = lo + npc;
    for (int e = base + threadIdx.x; e < end; e += blockDim.x) {
        int d = dst[e];
        if (d >= lo && d < hi) {
            int p = atomicAdd(&cnt[d], 1);
            adj[(size_t)d * CAP + p] = src[e];
        }
    }
}

// --- stage W (fp32 64x64) into B-fragment order (bf16) in LDS -------------
__device__ inline void stage_W(const float* __restrict__ W, unsigned short* Wb, int t) {
#pragma unroll
    for (int e0 = 0; e0 < 2; e0++) {
        int e = t + e0 * 256;          // frag index 0..511
        int sc = e >> 6;               // s*4 + c
        int l  = e & 63;               // target lane
        int s = sc >> 2, c = sc & 3;
        int nn = c * 16 + (l & 15);
        int kb = s * 32 + (l >> 4) * 8;
        const float* wp = &W[(size_t)kb * 64 + nn];
        unsigned q0 = pack_bf16(wp[0 * 64], wp[1 * 64]);
        unsigned q1 = pack_bf16(wp[2 * 64], wp[3 * 64]);
        unsigned q2 = pack_bf16(wp[4 * 64], wp[5 * 64]);
        unsigned q3 = pack_bf16(wp[6 * 64], wp[7 * 64]);
        *(uint4*)&Wb[e * 8] = make_uint4(q0, q1, q2, q3);
    }
}

// --- planar g = dinv ⊙ (in @ W) via MFMA; 64 rows/block (layer 1 only) ----
__global__ __launch_bounds__(256, 4) void gemm_kernel(const float* __restrict__ in,
                                                      const float* __restrict__ W,
                                                      const int* __restrict__ cnt,
                                                      unsigned short* __restrict__ gLo,
                                                      unsigned short* __restrict__ gHi,
                                                      int n) {
    __shared__ unsigned short Wb[512 * 8];     // B-frags, then out-tile alias
    int t = threadIdx.x;
    stage_W(W, Wb, t);

    int wv = t >> 6;
    int lane = t & 63;
    int quad = lane >> 4;
    int m16 = lane & 15;

    int rowA = blockIdx.x * 64 + wv * 16 + m16;
    union { bf16x8 v; uint4 u; } a0, a1;
    {
        float4 f0 = make_float4(0, 0, 0, 0), f1 = f0, f2 = f0, f3 = f0;
        if (rowA < n) {
            const float* rp = &in[(size_t)rowA * 64];
            f0 = *(const float4*)&rp[quad * 8];
            f1 = *(const float4*)&rp[quad * 8 + 4];
            f2 = *(const float4*)&rp[32 + quad * 8];
            f3 = *(const float4*)&rp[32 + quad * 8 + 4];
        }
        a0.u = make_uint4(pack_bf16(f0.x, f0.y), pack_bf16(f0.z, f0.w),
                          pack_bf16(f1.x, f1.y), pack_bf16(f1.z, f1.w));
        a1.u = make_uint4(pack_bf16(f2.x, f2.y), pack_bf16(f2.z, f2.w),
                          pack_bf16(f3.x, f3.y), pack_bf16(f3.z, f3.w));
    }
    __syncthreads();

    f32x4 acc[4];
#pragma unroll
    for (int c = 0; c < 4; c++) {
        bf16x8 b0 = *(const bf16x8*)&Wb[((size_t)(0 * 4 + c) * 64 + lane) * 8];
        bf16x8 b1 = *(const bf16x8*)&Wb[((size_t)(1 * 4 + c) * 64 + lane) * 8];
        f32x4 z = {0.f, 0.f, 0.f, 0.f};
        z = __builtin_amdgcn_mfma_f32_16x16x32_bf16(a0.v, b0, z, 0, 0, 0);
        z = __builtin_amdgcn_mfma_f32_16x16x32_bf16(a1.v, b1, z, 0, 0, 0);
        acc[c] = z;
    }

    int lrow = wv * 16 + quad * 4;            // local row base 0..63
    float dv[4];
#pragma unroll
    for (int r = 0; r < 4; r++) {
        int row = blockIdx.x * 64 + lrow + r;
        dv[r] = (row < n) ? rsqrtf((float)(cnt[row] + 1)) : 0.f;
    }
    __syncthreads();                          // Wb B-frag reads all done
    unsigned short* Ofrag = Wb;               // 64x64 ushort = 8KB alias
#pragma unroll
    for (int c = 0; c < 4; c++) {
#pragma unroll
        for (int r = 0; r < 4; r++)
            Ofrag[(size_t)(lrow + r) * 64 + c * 16 + m16] = to_bf16(acc[c][r] * dv[r]);
    }
    __syncthreads();
#pragma unroll
    for (int it = 0; it < 2; it++) {
        int unit = t + it * 256;              // 512 units: 64 rows x 8 chunks
        int row = unit >> 3, chv = unit & 7;
        int grow = blockIdx.x * 64 + row;
        if (grow < n) {
            unsigned short* op = (chv < 4) ? gLo : gHi;
            *(uint4*)&op[(size_t)grow * 32 + (chv & 3) * 8] =
                *(const uint4*)&Ofrag[(size_t)row * 64 + chv * 8];
        }
    }
}

// --- fused agg(l) + gemm(l+1); 32 nodes/block; planar 2-pass gather -------
template <int WRITE_H, int RES_BF16>
__global__ __launch_bounds__(256, 4) void aggemm_kernel(
        const unsigned short* __restrict__ gLo,
        const unsigned short* __restrict__ gHi,
        const int* __restrict__ cnt,
        const int* __restrict__ adj,
        const float* __restrict__ bias,
        const void* __restrict__ res_p,
        const float* __restrict__ W,
        unsigned short* __restrict__ h_out,   // bf16 h (if WRITE_H)
        unsigned short* __restrict__ goLo,
        unsigned short* __restrict__ goHi,
        int n) {
    __shared__ unsigned short Wb[512 * 8];     // 8 KB B-frags
    __shared__ unsigned short Afrag[2048];     // 4 KB A-frags, then out-tile
    __shared__ float dsh[32];                  // per-node dinv for Phase B
    int t = threadIdx.x;

    // ---- Phase A: aggregate 32 nodes; lanes 0-3 Lo plane, 4-7 Hi plane ---
    int r  = t >> 3;                   // node-in-block 0..31
    int lg = t & 7;
    const int c8 = lg * 8;             // full-row feature base (epilogue)
    const int po = (lg & 3) * 8;       // 16B offset within the 32-col plane
    int i = blockIdx.x * 32 + r;
    bool valid = i < n;
    int deg = valid ? cnt[i] : 0;
    const int* lst = adj + (size_t)i * CAP;    // dereferenced only if deg>0
    const unsigned short* mp = (lg < 4) ? gLo : gHi;

    float a0 = 0.f, a1 = 0.f, a2 = 0.f, a3 = 0.f;
    float a4 = 0.f, a5 = 0.f, a6 = 0.f, a7 = 0.f;
    float r0 = 0.f, r1 = 0.f, r2 = 0.f, r3 = 0.f;
    float r4 = 0.f, r5 = 0.f, r6 = 0.f, r7 = 0.f;
    if (valid) {
        {   // self loop (own plane row)
            uint4 v = *(const uint4*)&mp[(size_t)i * 32 + po];
            acc_bf16x2(v.x, a0, a1); acc_bf16x2(v.y, a2, a3);
            acc_bf16x2(v.z, a4, a5); acc_bf16x2(v.w, a6, a7);
        }
        if (RES_BF16) {                // residual: bf16 h1, full-row layout
            const unsigned short* rp = (const unsigned short*)res_p;
            uint4 rv = *(const uint4*)&rp[(size_t)i * 64 + c8];
            acc_bf16x2(rv.x, r0, r1); acc_bf16x2(rv.y, r2, r3);
            acc_bf16x2(rv.z, r4, r5); acc_bf16x2(rv.w, r6, r7);
        } else {                       // fp32 residual (x)
            const float* rp = (const float*)res_p;
            float4 q0 = *(const float4*)&rp[(size_t)i * 64 + c8];
            float4 q1 = *(const float4*)&rp[(size_t)i * 64 + c8 + 4];
            r0 = q0.x; r1 = q0.y; r2 = q0.z; r3 = q0.w;
            r4 = q1.x; r5 = q1.y; r6 = q1.z; r7 = q1.w;
        }
    }
    // pass A: Lo plane (lanes 0-3 of each node-group)
    if (lg < 4)
        gather_plane(mp, lst, deg, po, a0, a1, a2, a3, a4, a5, a6, a7);
    __syncthreads();                   // temporal window split (and no merge)
    // pass B: Hi plane (lanes 4-7)
    if (lg >= 4)
        gather_plane(mp, lst, deg, po, a0, a1, a2, a3, a4, a5, a6, a7);

    float dvv = 0.f;
    float v0 = 0.f, v1 = 0.f, v2 = 0.f, v3 = 0.f;
    float v4 = 0.f, v5 = 0.f, v6 = 0.f, v7 = 0.f;
    if (valid) {
        dvv = rsqrtf((float)(deg + 1));
        float4 b0 = *(const float4*)&bias[c8];
        float4 b1 = *(const float4*)&bias[c8 + 4];
        v0 = fmaxf(dvv * a0 + b0.x, 0.f) + r0;
        v1 = fmaxf(dvv * a1 + b0.y, 0.f) + r1;
        v2 = fmaxf(dvv * a2 + b0.z, 0.f) + r2;
        v3 = fmaxf(dvv * a3 + b0.w, 0.f) + r3;
        v4 = fmaxf(dvv * a4 + b1.x, 0.f) + r4;
        v5 = fmaxf(dvv * a5 + b1.y, 0.f) + r5;
        v6 = fmaxf(dvv * a6 + b1.z, 0.f) + r6;
        v7 = fmaxf(dvv * a7 + b1.w, 0.f) + r7;
    }
    // pack h row chunk once: reused for h_out write and A-frag deposit
    uint4 pk;
    pk.x = pack_bf16(v0, v1);
    pk.y = pack_bf16(v2, v3);
    pk.z = pack_bf16(v4, v5);
    pk.w = pack_bf16(v6, v7);
    if (WRITE_H && valid)
        *(uint4*)&h_out[(size_t)i * 64 + c8] = pk;
    // stage W after the gather (R15): latency hides under other waves' A.
    stage_W(W, Wb, t);
    {
        int sA = r >> 4, mA = r & 15;
        *(uint4*)&Afrag[((size_t)(sA * 8 + lg) * 16 + mA) * 8] = pk;
        if (lg == 0) dsh[r] = dvv;
    }
    __syncthreads();

    // ---- Phase B: MFMA gemm on the 32-row tile ----
    int wv = t >> 6;
    int lane = t & 63;
    int quad = lane >> 4;
    int m16 = lane & 15;
    int sB = wv & 1;                   // row sub-tile 0..1
    int ch = wv >> 1;                  // col half 0..1
    bf16x8 af0 = *(const bf16x8*)&Afrag[((size_t)(sB * 8 + quad) * 16 + m16) * 8];
    bf16x8 af1 = *(const bf16x8*)&Afrag[((size_t)(sB * 8 + 4 + quad) * 16 + m16) * 8];
    int lrow = sB * 16 + quad * 4;     // local row 0..31
    float dv2[4];
#pragma unroll
    for (int rr = 0; rr < 4; rr++)
        dv2[rr] = dsh[lrow + rr];
    __syncthreads();                   // all A-frag reads done before overwrite
    f32x4 acc[2];
#pragma unroll
    for (int c2 = 0; c2 < 2; c2++) {
        int c = ch * 2 + c2;
        bf16x8 b0 = *(const bf16x8*)&Wb[((size_t)(0 * 4 + c) * 64 + lane) * 8];
        bf16x8 b1 = *(const bf16x8*)&Wb[((size_t)(1 * 4 + c) * 64 + lane) * 8];
        f32x4 z = {0.f, 0.f, 0.f, 0.f};
        z = __builtin_amdgcn_mfma_f32_16x16x32_bf16(af0, b0, z, 0, 0, 0);
        z = __builtin_amdgcn_mfma_f32_16x16x32_bf16(af1, b1, z, 0, 0, 0);
        acc[c2] = z;
    }
    // stage out-tile into Afrag [32][64] for coalesced planar stores
#pragma unroll
    for (int c2 = 0; c2 < 2; c2++) {
        int c = ch * 2 + c2;
#pragma unroll
        for (int rr = 0; rr < 4; rr++)
            Afrag[(size_t)(lrow + rr) * 64 + c * 16 + m16] = to_bf16(acc[c2][rr] * dv2[rr]);
    }
    __syncthreads();
    {
        int orow = blockIdx.x * 32 + r;
        if (orow < n) {
            unsigned short* op = (lg < 4) ? goLo : goHi;
            *(uint4*)&op[(size_t)orow * 32 + po] =
                *(const uint4*)&Afrag[(size_t)r * 64 + c8];
        }
    }
}

// --- final aggregation: planar 2-pass gather, fp32 out --------------------
__global__ __launch_bounds__(256, 4) void agg_kernel(const unsigned short* __restrict__ gLo,
                                                     const unsigned short* __restrict__ gHi,
                                                     const int* __restrict__ cnt,
                                                     const int* __restrict__ adj,
                                                     const float* __restrict__ bias,
                                                     float* __restrict__ out, int n) {
    int t = threadIdx.x;
    int lg = t & 7;
    int r = t >> 3;
    int i = blockIdx.x * 32 + r;
    bool valid = i < n;
    int deg = valid ? cnt[i] : 0;
    const int* lst = adj + (size_t)i * CAP;
    const int c8 = lg * 8;
    const int po = (lg & 3) * 8;
    const unsigned short* mp = (lg < 4) ? gLo : gHi;
    float a0 = 0.f, a1 = 0.f, a2 = 0.f, a3 = 0.f;
    float a4 = 0.f, a5 = 0.f, a6 = 0.f, a7 = 0.f;
    if (valid) {   // self loop
        uint4 v = *(const uint4*)&mp[(size_t)i * 32 + po];
        acc_bf16x2(v.x, a0, a1); acc_bf16x2(v.y, a2, a3);
        acc_bf16x2(v.z, a4, a5); acc_bf16x2(v.w, a6, a7);
    }
    if (lg < 4)
        gather_plane(mp, lst, deg, po, a0, a1, a2, a3, a4, a5, a6, a7);
    __syncthreads();                   // temporal window split
    if (lg >= 4)
        gather_plane(mp, lst, deg, po, a0, a1, a2, a3, a4, a5, a6, a7);
    if (!valid) return;
    float dv = rsqrtf((float)(deg + 1));
    float4 b0 = *(const float4*)&bias[c8];
    float4 b1 = *(const float4*)&bias[c8 + 4];
    float4 o0, o1;
    o0.x = dv * a0 + b0.x; o0.y = dv * a1 + b0.y;
    o0.z = dv * a2 + b0.z; o0.w = dv * a3 + b0.w;
    o1.x = dv * a4 + b1.x; o1.y = dv * a5 + b1.y;
    o1.z = dv * a6 + b1.z; o1.w = dv * a7 + b1.w;
    size_t rowoff = (size_t)i * 64 + c8;
    *(float4*)&out[rowoff] = o0;
    *(float4*)&out[rowoff + 4] = o1;
}

extern "C" void kernel_launch(void* const* d_in, const int* in_sizes, int n_in,
                              void* d_out, int out_size, void* d_ws, size_t ws_size,
                              hipStream_t stream) {
    const float* x  = (const float*)d_in[0];
    const int*   ei = (const int*)d_in[1];
    const float* W1 = (const float*)d_in[2];
    const float* b1 = (const float*)d_in[3];
    const float* W2 = (const float*)d_in[4];
    const float* b2 = (const float*)d_in[5];
    const float* W3 = (const float*)d_in[6];
    const float* b3 = (const float*)d_in[7];
    float* out = (float*)d_out;

    const int N = in_sizes[0] / 64;
    const int E = in_sizes[1] / 2;
    const int* src = ei;
    const int* dst = ei + E;
    const int npc = (N + 7) / 8;
    const int nEdgeChunks = (E + EDGE_CHUNK - 1) / EDGE_CHUNK;

    // workspace layout (planar g tables: each plane N x 32 bf16 = 3.2MB)
    char* p = (char*)d_ws;
    const int Na = ((N + 63) / 64) * 64;
    int*            cnt  = (int*)p;            p += (size_t)Na * 4;
    int*            adj  = (int*)p;            p += ((size_t)N + 1) * CAP * 4;
    unsigned short* gaLo = (unsigned short*)p; p += (size_t)N * 32 * 2;
    unsigned short* gaHi = (unsigned short*)p; p += (size_t)N * 32 * 2;
    unsigned short* gbLo = (unsigned short*)p; p += (size_t)N * 32 * 2;
    unsigned short* gbHi = (unsigned short*)p; p += (size_t)N * 32 * 2;
    unsigned short* h1   = (unsigned short*)p; p += (size_t)N * 64 * 2;  // bf16

    const int tileBlocks = (N + 63) / 64;   // gemm (64-row MFMA tiles)
    const int halfBlocks = (N + 31) / 32;   // aggemm + final agg (32 nodes)

    // --- bucket adjacency build (ws re-poisoned every call) ---
    hipMemsetAsync(cnt, 0, (size_t)N * 4, stream);
    fill_kernel<<<nEdgeChunks * 8, 256, 0, stream>>>(src, dst, cnt, adj, E, npc);

    // --- layer 1 gemm: ga = dinv ⊙ (x@W1)  (planar) ---
    gemm_kernel<<<tileBlocks, 256, 0, stream>>>(x, W1, cnt, gaLo, gaHi, N);
    // --- fused: h1 = relu(agg(ga))+x (bf16) ; gb = dinv ⊙ (h1@W2) ---
    aggemm_kernel<1, 0><<<halfBlocks, 256, 0, stream>>>(gaLo, gaHi, cnt, adj, b1,
                                                        (const void*)x, W2, h1,
                                                        gbLo, gbHi, N);
    // --- fused: h2 = relu(agg(gb))+h1 ; ga = dinv ⊙ (h2@W3) ---
    aggemm_kernel<0, 1><<<halfBlocks, 256, 0, stream>>>(gbLo, gbHi, cnt, adj, b2,
                                                        (const void*)h1, W3, nullptr,
                                                        gaLo, gaHi, N);
    // --- final: out = agg(ga) + b3 ---
    agg_kernel<<<halfBlocks, 256, 0, stream>>>(gaLo, gaHi, cnt, adj, b3, out, N);
}

// Round 9
// 186.384 us; speedup vs baseline: 1.3016x; 1.1262x over previous
//
#include <hip/hip_runtime.h>
#include <hip/hip_bf16.h>

// ---------------------------------------------------------------------------
// GCN 3-layer, N=50000, E=800000, D=64, fp32 in/out.
// R22: plane-windowed gather with ALL lanes active. R21's planar split
// regressed (+27us) because each pass idled half the lanes (issue-time 2x)
// — the windowing mechanism itself wasn't falsified. R20 counters: agg
// FETCH 84.5MB vs ~44MB compulsory (8 XCDs x 86% of 6.4MB table) => ~40MB
// L2 capacity thrash (5.5MB/XCD working set vs 4MB L2); both measured
// configs pinned at ~3.5TB/s => bytes-limited. Fix: 4 lanes/node x 32
// nodes = 128-thread blocks (launch_bounds(128,4), ~6 blocks/CU in one
// round). Pass A: all lanes gather Lo plane (row = 4x16B = one 64B line);
// barrier; pass B: Hi plane. Same requests/bytes as R15, zero idle lanes,
// 3.2MB per-pass footprint -> 2.75MB/XCD working set fits L2. Thread
// carries 16 acc (8 lo + 8 hi); adjacency walked twice (+3.2MB streaming,
// negligible). Per-feature accumulation order unchanged (absmax stable).
// Phase B MFMA: 2 waves x 8 MFMAs on the 32-row tile; planar LDS-staged
// stores. gemm1 (256t, planar out) and fill unchanged.
// Failed levers (kept out): R16 lo/hi list split, R18 persistent barrier,
// R20 (256,8) VGPR=32, R21 half-lane planes. Kept: R19 bf16 h1 + staged
// stores, R15 index prefetch + stage_W-after-gather, R14 32-node blocks,
// R13 agg+gemm fusion, R3/R4 XCD fill, R6 bf16 table, R8 MFMA.
// ---------------------------------------------------------------------------

#define CAP 64
#define EDGE_CHUNK 1024

typedef __attribute__((ext_vector_type(8))) short bf16x8;
typedef __attribute__((ext_vector_type(4))) float f32x4;

// --- pack two fp32 -> bf16x2 (RNE) ----------------------------------------
__device__ inline unsigned pack_bf16(float a, float b) {
    union { float f; unsigned i; } ua, ub;
    ua.f = a; ub.f = b;
    unsigned x = (ua.i + 0x7fffu + ((ua.i >> 16) & 1u)) >> 16;
    unsigned y = (ub.i + 0x7fffu + ((ub.i >> 16) & 1u)) >> 16;
    return x | (y << 16);
}
__device__ inline unsigned short to_bf16(float a) {
    union { float f; unsigned i; } u; u.f = a;
    return (unsigned short)((u.i + 0x7fffu + ((u.i >> 16) & 1u)) >> 16);
}
// --- accumulate bf16x2 (packed uint) into two floats ----------------------
__device__ inline void acc_bf16x2(unsigned u, float& a, float& b) {
    union { unsigned i; float f; } lo, hi;
    lo.i = u << 16;
    hi.i = u & 0xffff0000u;
    a += lo.f; b += hi.f;
}

// --- planar row gather: rows of 32 bf16 (64B); lane reads 16B at off ------
// Index prefetch one batch ahead (R15 form). All lanes active.
__device__ inline void gather_plane(const unsigned short* __restrict__ gp,
                                    const int* __restrict__ lst, int deg, int off,
                                    float& a0, float& a1, float& a2, float& a3,
                                    float& a4, float& a5, float& a6, float& a7) {
    int nfull = deg >> 3;              // full 8-batches
    int4 ja, jb;
    if (nfull > 0) { ja = *(const int4*)&lst[0]; jb = *(const int4*)&lst[4]; }
    for (int b = 0; b < nfull; b++) {
        int4 na = ja, nb = jb;         // prefetch next batch's indices
        if (b + 1 < nfull) {
            na = *(const int4*)&lst[(b + 1) * 8];
            nb = *(const int4*)&lst[(b + 1) * 8 + 4];
        }
        uint4 w0 = *(const uint4*)&gp[(size_t)ja.x * 32 + off];
        uint4 w1 = *(const uint4*)&gp[(size_t)ja.y * 32 + off];
        uint4 w2 = *(const uint4*)&gp[(size_t)ja.z * 32 + off];
        uint4 w3 = *(const uint4*)&gp[(size_t)ja.w * 32 + off];
        uint4 w4 = *(const uint4*)&gp[(size_t)jb.x * 32 + off];
        uint4 w5 = *(const uint4*)&gp[(size_t)jb.y * 32 + off];
        uint4 w6 = *(const uint4*)&gp[(size_t)jb.z * 32 + off];
        uint4 w7 = *(const uint4*)&gp[(size_t)jb.w * 32 + off];
        acc_bf16x2(w0.x, a0, a1); acc_bf16x2(w0.y, a2, a3);
        acc_bf16x2(w0.z, a4, a5); acc_bf16x2(w0.w, a6, a7);
        acc_bf16x2(w1.x, a0, a1); acc_bf16x2(w1.y, a2, a3);
        acc_bf16x2(w1.z, a4, a5); acc_bf16x2(w1.w, a6, a7);
        acc_bf16x2(w2.x, a0, a1); acc_bf16x2(w2.y, a2, a3);
        acc_bf16x2(w2.z, a4, a5); acc_bf16x2(w2.w, a6, a7);
        acc_bf16x2(w3.x, a0, a1); acc_bf16x2(w3.y, a2, a3);
        acc_bf16x2(w3.z, a4, a5); acc_bf16x2(w3.w, a6, a7);
        acc_bf16x2(w4.x, a0, a1); acc_bf16x2(w4.y, a2, a3);
        acc_bf16x2(w4.z, a4, a5); acc_bf16x2(w4.w, a6, a7);
        acc_bf16x2(w5.x, a0, a1); acc_bf16x2(w5.y, a2, a3);
        acc_bf16x2(w5.z, a4, a5); acc_bf16x2(w5.w, a6, a7);
        acc_bf16x2(w6.x, a0, a1); acc_bf16x2(w6.y, a2, a3);
        acc_bf16x2(w6.z, a4, a5); acc_bf16x2(w6.w, a6, a7);
        acc_bf16x2(w7.x, a0, a1); acc_bf16x2(w7.y, a2, a3);
        acc_bf16x2(w7.z, a4, a5); acc_bf16x2(w7.w, a6, a7);
        ja = na; jb = nb;
    }
    int k = nfull * 8;
    if (k + 4 <= deg) {
        int4 j4 = *(const int4*)&lst[k];
        uint4 w0 = *(const uint4*)&gp[(size_t)j4.x * 32 + off];
        uint4 w1 = *(const uint4*)&gp[(size_t)j4.y * 32 + off];
        uint4 w2 = *(const uint4*)&gp[(size_t)j4.z * 32 + off];
        uint4 w3 = *(const uint4*)&gp[(size_t)j4.w * 32 + off];
        acc_bf16x2(w0.x, a0, a1); acc_bf16x2(w0.y, a2, a3);
        acc_bf16x2(w0.z, a4, a5); acc_bf16x2(w0.w, a6, a7);
        acc_bf16x2(w1.x, a0, a1); acc_bf16x2(w1.y, a2, a3);
        acc_bf16x2(w1.z, a4, a5); acc_bf16x2(w1.w, a6, a7);
        acc_bf16x2(w2.x, a0, a1); acc_bf16x2(w2.y, a2, a3);
        acc_bf16x2(w2.z, a4, a5); acc_bf16x2(w2.w, a6, a7);
        acc_bf16x2(w3.x, a0, a1); acc_bf16x2(w3.y, a2, a3);
        acc_bf16x2(w3.z, a4, a5); acc_bf16x2(w3.w, a6, a7);
        k += 4;
    }
    for (; k < deg; k++) {
        uint4 v = *(const uint4*)&gp[(size_t)lst[k] * 32 + off];
        acc_bf16x2(v.x, a0, a1); acc_bf16x2(v.y, a2, a3);
        acc_bf16x2(v.z, a4, a5); acc_bf16x2(v.w, a6, a7);
    }
}

// --- fused count+place: slot = atomicAdd(cnt), XCD-partitioned by dst -----
__global__ void fill_kernel(const int* __restrict__ src, const int* __restrict__ dst,
                            int* __restrict__ cnt, int* __restrict__ adj,
                            int E, int npc) {
    int cls = blockIdx.x & 7;          // -> XCD (round-robin heuristic)
    int base = (blockIdx.x >> 3) * EDGE_CHUNK;
    int end = min(base + EDGE_CHUNK, E);
    int lo = cls * npc, hi = lo + npc;
    for (int e = base + threadIdx.x; e < end; e += blockDim.x) {
        int d = dst[e];
        if (d >= lo && d < hi) {
            int p = atomicAdd(&cnt[d], 1);
            adj[(size_t)d * CAP + p] = src[e];
        }
    }
}

// --- stage W (fp32 64x64) into B-fragment order (bf16) in LDS -------------
template <int NT>
__device__ inline void stage_W(const float* __restrict__ W, unsigned short* Wb, int t) {
#pragma unroll
    for (int e0 = 0; e0 < 512 / NT; e0++) {
        int e = t + e0 * NT;           // frag index 0..511
        int sc = e >> 6;               // s*4 + c
        int l  = e & 63;               // target lane
        int s = sc >> 2, c = sc & 3;
        int nn = c * 16 + (l & 15);
        int kb = s * 32 + (l >> 4) * 8;
        const float* wp = &W[(size_t)kb * 64 + nn];
        unsigned q0 = pack_bf16(wp[0 * 64], wp[1 * 64]);
        unsigned q1 = pack_bf16(wp[2 * 64], wp[3 * 64]);
        unsigned q2 = pack_bf16(wp[4 * 64], wp[5 * 64]);
        unsigned q3 = pack_bf16(wp[6 * 64], wp[7 * 64]);
        *(uint4*)&Wb[e * 8] = make_uint4(q0, q1, q2, q3);
    }
}

// --- planar g = dinv ⊙ (in @ W) via MFMA; 64 rows/block (layer 1 only) ----
__global__ __launch_bounds__(256, 4) void gemm_kernel(const float* __restrict__ in,
                                                      const float* __restrict__ W,
                                                      const int* __restrict__ cnt,
                                                      unsigned short* __restrict__ gLo,
                                                      unsigned short* __restrict__ gHi,
                                                      int n) {
    __shared__ unsigned short Wb[512 * 8];     // B-frags, then out-tile alias
    int t = threadIdx.x;
    stage_W<256>(W, Wb, t);

    int wv = t >> 6;
    int lane = t & 63;
    int quad = lane >> 4;
    int m16 = lane & 15;

    int rowA = blockIdx.x * 64 + wv * 16 + m16;
    union { bf16x8 v; uint4 u; } a0, a1;
    {
        float4 f0 = make_float4(0, 0, 0, 0), f1 = f0, f2 = f0, f3 = f0;
        if (rowA < n) {
            const float* rp = &in[(size_t)rowA * 64];
            f0 = *(const float4*)&rp[quad * 8];
            f1 = *(const float4*)&rp[quad * 8 + 4];
            f2 = *(const float4*)&rp[32 + quad * 8];
            f3 = *(const float4*)&rp[32 + quad * 8 + 4];
        }
        a0.u = make_uint4(pack_bf16(f0.x, f0.y), pack_bf16(f0.z, f0.w),
                          pack_bf16(f1.x, f1.y), pack_bf16(f1.z, f1.w));
        a1.u = make_uint4(pack_bf16(f2.x, f2.y), pack_bf16(f2.z, f2.w),
                          pack_bf16(f3.x, f3.y), pack_bf16(f3.z, f3.w));
    }
    __syncthreads();

    f32x4 acc[4];
#pragma unroll
    for (int c = 0; c < 4; c++) {
        bf16x8 b0 = *(const bf16x8*)&Wb[((size_t)(0 * 4 + c) * 64 + lane) * 8];
        bf16x8 b1 = *(const bf16x8*)&Wb[((size_t)(1 * 4 + c) * 64 + lane) * 8];
        f32x4 z = {0.f, 0.f, 0.f, 0.f};
        z = __builtin_amdgcn_mfma_f32_16x16x32_bf16(a0.v, b0, z, 0, 0, 0);
        z = __builtin_amdgcn_mfma_f32_16x16x32_bf16(a1.v, b1, z, 0, 0, 0);
        acc[c] = z;
    }

    int lrow = wv * 16 + quad * 4;            // local row base 0..63
    float dv[4];
#pragma unroll
    for (int r = 0; r < 4; r++) {
        int row = blockIdx.x * 64 + lrow + r;
        dv[r] = (row < n) ? rsqrtf((float)(cnt[row] + 1)) : 0.f;
    }
    __syncthreads();                          // Wb B-frag reads all done
    unsigned short* Ofrag = Wb;               // 64x64 ushort = 8KB alias
#pragma unroll
    for (int c = 0; c < 4; c++) {
#pragma unroll
        for (int r = 0; r < 4; r++)
            Ofrag[(size_t)(lrow + r) * 64 + c * 16 + m16] = to_bf16(acc[c][r] * dv[r]);
    }
    __syncthreads();
#pragma unroll
    for (int it = 0; it < 2; it++) {
        int unit = t + it * 256;              // 512 units: 64 rows x 8 chunks
        int row = unit >> 3, chv = unit & 7;
        int grow = blockIdx.x * 64 + row;
        if (grow < n) {
            unsigned short* op = (chv < 4) ? gLo : gHi;
            *(uint4*)&op[(size_t)grow * 32 + (chv & 3) * 8] =
                *(const uint4*)&Ofrag[(size_t)row * 64 + chv * 8];
        }
    }
}

// --- fused agg(l) + gemm(l+1); 32 nodes/block; 128 threads (R22) ----------
// Phase A: 4 lanes/node, two ALL-LANE plane passes (Lo, barrier, Hi).
// Epilogue h = relu(dinv*sum+bias)+res; h written bf16 (WRITE_H); deposit
// h (2 chunks) into A-frag LDS + dinv into LDS. Phase B: 2 waves x 8 MFMAs
// on the 32-row tile; out-tile staged into Afrag; coalesced planar stores.
template <int WRITE_H, int RES_BF16>
__global__ __launch_bounds__(128, 4) void aggemm_kernel(
        const unsigned short* __restrict__ gLo,
        const unsigned short* __restrict__ gHi,
        const int* __restrict__ cnt,
        const int* __restrict__ adj,
        const float* __restrict__ bias,
        const void* __restrict__ res_p,
        const float* __restrict__ W,
        unsigned short* __restrict__ h_out,   // bf16 h (if WRITE_H)
        unsigned short* __restrict__ goLo,
        unsigned short* __restrict__ goHi,
        int n) {
    __shared__ unsigned short Wb[512 * 8];     // 8 KB B-frags
    __shared__ unsigned short Afrag[2048];     // 4 KB A-frags, then out-tile
    __shared__ float dsh[32];                  // per-node dinv for Phase B
    int t = threadIdx.x;

    // ---- Phase A: 32 nodes, 4 lanes/node, two plane passes ----
    int r  = t >> 2;                   // node-in-block 0..31
    int l4 = t & 3;
    const int po = l4 * 8;             // 16B offset within a 32-col plane
    int i = blockIdx.x * 32 + r;
    bool valid = i < n;
    int deg = valid ? cnt[i] : 0;
    const int* lst = adj + (size_t)i * CAP;

    float la0 = 0.f, la1 = 0.f, la2 = 0.f, la3 = 0.f;
    float la4 = 0.f, la5 = 0.f, la6 = 0.f, la7 = 0.f;
    float ha0 = 0.f, ha1 = 0.f, ha2 = 0.f, ha3 = 0.f;
    float ha4 = 0.f, ha5 = 0.f, ha6 = 0.f, ha7 = 0.f;

    if (valid) {   // self loop, lo plane
        uint4 v = *(const uint4*)&gLo[(size_t)i * 32 + po];
        acc_bf16x2(v.x, la0, la1); acc_bf16x2(v.y, la2, la3);
        acc_bf16x2(v.z, la4, la5); acc_bf16x2(v.w, la6, la7);
    }
    gather_plane(gLo, lst, deg, po, la0, la1, la2, la3, la4, la5, la6, la7);
    __syncthreads();                   // plane window boundary
    if (valid) {   // self loop, hi plane
        uint4 v = *(const uint4*)&gHi[(size_t)i * 32 + po];
        acc_bf16x2(v.x, ha0, ha1); acc_bf16x2(v.y, ha2, ha3);
        acc_bf16x2(v.z, ha4, ha5); acc_bf16x2(v.w, ha6, ha7);
    }
    gather_plane(gHi, lst, deg, po, ha0, ha1, ha2, ha3, ha4, ha5, ha6, ha7);

    // ---- epilogue: dinv, bias, relu, residual; pack ----
    float dvv = 0.f;
    uint4 pkL, pkH;
    {
        float v0 = 0.f, v1 = 0.f, v2 = 0.f, v3 = 0.f;
        float v4 = 0.f, v5 = 0.f, v6 = 0.f, v7 = 0.f;
        float w0 = 0.f, w1 = 0.f, w2 = 0.f, w3 = 0.f;
        float w4 = 0.f, w5 = 0.f, w6 = 0.f, w7 = 0.f;
        if (valid) {
            dvv = rsqrtf((float)(deg + 1));
            float4 bL0 = *(const float4*)&bias[po];
            float4 bL1 = *(const float4*)&bias[po + 4];
            float4 bH0 = *(const float4*)&bias[32 + po];
            float4 bH1 = *(const float4*)&bias[32 + po + 4];
            float rL[8], rH[8];
            if (RES_BF16) {
                const unsigned short* rp = (const unsigned short*)res_p;
                uint4 rv0 = *(const uint4*)&rp[(size_t)i * 64 + po];
                uint4 rv1 = *(const uint4*)&rp[(size_t)i * 64 + 32 + po];
                acc_bf16x2(rv0.x, rL[0] = 0, rL[1] = 0);
                // (acc into zero-initialized: do explicit)
                rL[0] = 0; rL[1] = 0; rL[2] = 0; rL[3] = 0;
                rL[4] = 0; rL[5] = 0; rL[6] = 0; rL[7] = 0;
                rH[0] = 0; rH[1] = 0; rH[2] = 0; rH[3] = 0;
                rH[4] = 0; rH[5] = 0; rH[6] = 0; rH[7] = 0;
                acc_bf16x2(rv0.x, rL[0], rL[1]); acc_bf16x2(rv0.y, rL[2], rL[3]);
                acc_bf16x2(rv0.z, rL[4], rL[5]); acc_bf16x2(rv0.w, rL[6], rL[7]);
                acc_bf16x2(rv1.x, rH[0], rH[1]); acc_bf16x2(rv1.y, rH[2], rH[3]);
                acc_bf16x2(rv1.z, rH[4], rH[5]); acc_bf16x2(rv1.w, rH[6], rH[7]);
            } else {
                const float* rp = (const float*)res_p;
                float4 q0 = *(const float4*)&rp[(size_t)i * 64 + po];
                float4 q1 = *(const float4*)&rp[(size_t)i * 64 + po + 4];
                float4 q2 = *(const float4*)&rp[(size_t)i * 64 + 32 + po];
                float4 q3 = *(const float4*)&rp[(size_t)i * 64 + 32 + po + 4];
                rL[0] = q0.x; rL[1] = q0.y; rL[2] = q0.z; rL[3] = q0.w;
                rL[4] = q1.x; rL[5] = q1.y; rL[6] = q1.z; rL[7] = q1.w;
                rH[0] = q2.x; rH[1] = q2.y; rH[2] = q2.z; rH[3] = q2.w;
                rH[4] = q3.x; rH[5] = q3.y; rH[6] = q3.z; rH[7] = q3.w;
            }
            v0 = fmaxf(dvv * la0 + bL0.x, 0.f) + rL[0];
            v1 = fmaxf(dvv * la1 + bL0.y, 0.f) + rL[1];
            v2 = fmaxf(dvv * la2 + bL0.z, 0.f) + rL[2];
            v3 = fmaxf(dvv * la3 + bL0.w, 0.f) + rL[3];
            v4 = fmaxf(dvv * la4 + bL1.x, 0.f) + rL[4];
            v5 = fmaxf(dvv * la5 + bL1.y, 0.f) + rL[5];
            v6 = fmaxf(dvv * la6 + bL1.z, 0.f) + rL[6];
            v7 = fmaxf(dvv * la7 + bL1.w, 0.f) + rL[7];
            w0 = fmaxf(dvv * ha0 + bH0.x, 0.f) + rH[0];
            w1 = fmaxf(dvv * ha1 + bH0.y, 0.f) + rH[1];
            w2 = fmaxf(dvv * ha2 + bH0.z, 0.f) + rH[2];
            w3 = fmaxf(dvv * ha3 + bH0.w, 0.f) + rH[3];
            w4 = fmaxf(dvv * ha4 + bH1.x, 0.f) + rH[4];
            w5 = fmaxf(dvv * ha5 + bH1.y, 0.f) + rH[5];
            w6 = fmaxf(dvv * ha6 + bH1.z, 0.f) + rH[6];
            w7 = fmaxf(dvv * ha7 + bH1.w, 0.f) + rH[7];
        }
        pkL.x = pack_bf16(v0, v1); pkL.y = pack_bf16(v2, v3);
        pkL.z = pack_bf16(v4, v5); pkL.w = pack_bf16(v6, v7);
        pkH.x = pack_bf16(w0, w1); pkH.y = pack_bf16(w2, w3);
        pkH.z = pack_bf16(w4, w5); pkH.w = pack_bf16(w6, w7);
    }
    if (WRITE_H && valid) {
        *(uint4*)&h_out[(size_t)i * 64 + po]      = pkL;
        *(uint4*)&h_out[(size_t)i * 64 + 32 + po] = pkH;
    }
    // stage W after the gather: latency hides under other waves' Phase A.
    stage_W<128>(W, Wb, t);
    {
        int sA = r >> 4, mA = r & 15;          // A-frag slot math
        *(uint4*)&Afrag[((size_t)(sA * 8 + l4) * 16 + mA) * 8]     = pkL;  // chunks 0-3
        *(uint4*)&Afrag[((size_t)(sA * 8 + 4 + l4) * 16 + mA) * 8] = pkH;  // chunks 4-7
        if (l4 == 0) dsh[r] = dvv;
    }
    __syncthreads();

    // ---- Phase B: MFMA gemm on the 32-row tile (2 waves) ----
    int wv = t >> 6;                   // wave 0..1 -> row sub-tile
    int lane = t & 63;
    int quad = lane >> 4;
    int m16 = lane & 15;
    int sB = wv;
    bf16x8 af0 = *(const bf16x8*)&Afrag[((size_t)(sB * 8 + quad) * 16 + m16) * 8];
    bf16x8 af1 = *(const bf16x8*)&Afrag[((size_t)(sB * 8 + 4 + quad) * 16 + m16) * 8];
    int lrow = sB * 16 + quad * 4;     // local row 0..31
    float dv2[4];
#pragma unroll
    for (int rr = 0; rr < 4; rr++)
        dv2[rr] = dsh[lrow + rr];
    __syncthreads();                   // all A-frag reads done before overwrite
    f32x4 acc[4];
#pragma unroll
    for (int c = 0; c < 4; c++) {
        bf16x8 b0 = *(const bf16x8*)&Wb[((size_t)(0 * 4 + c) * 64 + lane) * 8];
        bf16x8 b1 = *(const bf16x8*)&Wb[((size_t)(1 * 4 + c) * 64 + lane) * 8];
        f32x4 z = {0.f, 0.f, 0.f, 0.f};
        z = __builtin_amdgcn_mfma_f32_16x16x32_bf16(af0, b0, z, 0, 0, 0);
        z = __builtin_amdgcn_mfma_f32_16x16x32_bf16(af1, b1, z, 0, 0, 0);
        acc[c] = z;
    }
    // stage out-tile into Afrag [32][64] for coalesced planar stores
#pragma unroll
    for (int c = 0; c < 4; c++) {
#pragma unroll
        for (int rr = 0; rr < 4; rr++)
            Afrag[(size_t)(lrow + rr) * 64 + c * 16 + m16] = to_bf16(acc[c][rr] * dv2[rr]);
    }
    __syncthreads();
#pragma unroll
    for (int it = 0; it < 2; it++) {
        int unit = t + it * 128;               // 256 units: 32 rows x 8 chunks
        int row = unit >> 3, chv = unit & 7;
        int orow = blockIdx.x * 32 + row;
        if (orow < n) {
            unsigned short* op = (chv < 4) ? goLo : goHi;
            *(uint4*)&op[(size_t)orow * 32 + (chv & 3) * 8] =
                *(const uint4*)&Afrag[(size_t)row * 64 + chv * 8];
        }
    }
}

// --- final aggregation: 4 lanes/node, two all-lane plane passes -----------
__global__ __launch_bounds__(128, 4) void agg_kernel(const unsigned short* __restrict__ gLo,
                                                     const unsigned short* __restrict__ gHi,
                                                     const int* __restrict__ cnt,
                                                     const int* __restrict__ adj,
                                                     const float* __restrict__ bias,
                                                     float* __restrict__ out, int n) {
    int t = threadIdx.x;
    int r = t >> 2;
    int l4 = t & 3;
    const int po = l4 * 8;
    int i = blockIdx.x * 32 + r;
    bool valid = i < n;
    int deg = valid ? cnt[i] : 0;
    const int* lst = adj + (size_t)i * CAP;
    float la0 = 0.f, la1 = 0.f, la2 = 0.f, la3 = 0.f;
    float la4 = 0.f, la5 = 0.f, la6 = 0.f, la7 = 0.f;
    float ha0 = 0.f, ha1 = 0.f, ha2 = 0.f, ha3 = 0.f;
    float ha4 = 0.f, ha5 = 0.f, ha6 = 0.f, ha7 = 0.f;
    if (valid) {   // self loop, lo plane
        uint4 v = *(const uint4*)&gLo[(size_t)i * 32 + po];
        acc_bf16x2(v.x, la0, la1); acc_bf16x2(v.y, la2, la3);
        acc_bf16x2(v.z, la4, la5); acc_bf16x2(v.w, la6, la7);
    }
    gather_plane(gLo, lst, deg, po, la0, la1, la2, la3, la4, la5, la6, la7);
    __syncthreads();                   // plane window boundary
    if (valid) {   // self loop, hi plane
        uint4 v = *(const uint4*)&gHi[(size_t)i * 32 + po];
        acc_bf16x2(v.x, ha0, ha1); acc_bf16x2(v.y, ha2, ha3);
        acc_bf16x2(v.z, ha4, ha5); acc_bf16x2(v.w, ha6, ha7);
    }
    gather_plane(gHi, lst, deg, po, ha0, ha1, ha2, ha3, ha4, ha5, ha6, ha7);
    if (!valid) return;
    float dv = rsqrtf((float)(deg + 1));
    float4 bL0 = *(const float4*)&bias[po];
    float4 bL1 = *(const float4*)&bias[po + 4];
    float4 bH0 = *(const float4*)&bias[32 + po];
    float4 bH1 = *(const float4*)&bias[32 + po + 4];
    float4 o0, o1, o2, o3;
    o0.x = dv * la0 + bL0.x; o0.y = dv * la1 + bL0.y;
    o0.z = dv * la2 + bL0.z; o0.w = dv * la3 + bL0.w;
    o1.x = dv * la4 + bL1.x; o1.y = dv * la5 + bL1.y;
    o1.z = dv * la6 + bL1.z; o1.w = dv * la7 + bL1.w;
    o2.x = dv * ha0 + bH0.x; o2.y = dv * ha1 + bH0.y;
    o2.z = dv * ha2 + bH0.z; o2.w = dv * ha3 + bH0.w;
    o3.x = dv * ha4 + bH1.x; o3.y = dv * ha5 + bH1.y;
    o3.z = dv * ha6 + bH1.z; o3.w = dv * ha7 + bH1.w;
    size_t base = (size_t)i * 64;
    *(float4*)&out[base + po]          = o0;
    *(float4*)&out[base + po + 4]      = o1;
    *(float4*)&out[base + 32 + po]     = o2;
    *(float4*)&out[base + 32 + po + 4] = o3;
}

extern "C" void kernel_launch(void* const* d_in, const int* in_sizes, int n_in,
                              void* d_out, int out_size, void* d_ws, size_t ws_size,
                              hipStream_t stream) {
    const float* x  = (const float*)d_in[0];
    const int*   ei = (const int*)d_in[1];
    const float* W1 = (const float*)d_in[2];
    const float* b1 = (const float*)d_in[3];
    const float* W2 = (const float*)d_in[4];
    const float* b2 = (const float*)d_in[5];
    const float* W3 = (const float*)d_in[6];
    const float* b3 = (const float*)d_in[7];
    float* out = (float*)d_out;

    const int N = in_sizes[0] / 64;
    const int E = in_sizes[1] / 2;
    const int* src = ei;
    const int* dst = ei + E;
    const int npc = (N + 7) / 8;
    const int nEdgeChunks = (E + EDGE_CHUNK - 1) / EDGE_CHUNK;

    // workspace layout (planar g tables: each plane N x 32 bf16 = 3.2MB)
    char* p = (char*)d_ws;
    const int Na = ((N + 63) / 64) * 64;
    int*            cnt  = (int*)p;            p += (size_t)Na * 4;
    int*            adj  = (int*)p;            p += ((size_t)N + 1) * CAP * 4;
    unsigned short* gaLo = (unsigned short*)p; p += (size_t)N * 32 * 2;
    unsigned short* gaHi = (unsigned short*)p; p += (size_t)N * 32 * 2;
    unsigned short* gbLo = (unsigned short*)p; p += (size_t)N * 32 * 2;
    unsigned short* gbHi = (unsigned short*)p; p += (size_t)N * 32 * 2;
    unsigned short* h1   = (unsigned short*)p; p += (size_t)N * 64 * 2;  // bf16

    const int tileBlocks = (N + 63) / 64;   // gemm (64-row MFMA tiles)
    const int halfBlocks = (N + 31) / 32;   // aggemm + final agg (32 nodes)

    // --- bucket adjacency build (ws re-poisoned every call) ---
    hipMemsetAsync(cnt, 0, (size_t)N * 4, stream);
    fill_kernel<<<nEdgeChunks * 8, 256, 0, stream>>>(src, dst, cnt, adj, E, npc);

    // --- layer 1 gemm: ga = dinv ⊙ (x@W1)  (planar) ---
    gemm_kernel<<<tileBlocks, 256, 0, stream>>>(x, W1, cnt, gaLo, gaHi, N);
    // --- fused: h1 = relu(agg(ga))+x (bf16) ; gb = dinv ⊙ (h1@W2) ---
    aggemm_kernel<1, 0><<<halfBlocks, 128, 0, stream>>>(gaLo, gaHi, cnt, adj, b1,
                                                        (const void*)x, W2, h1,
                                                        gbLo, gbHi, N);
    // --- fused: h2 = relu(agg(gb))+h1 ; ga = dinv ⊙ (h2@W3) ---
    aggemm_kernel<0, 1><<<halfBlocks, 128, 0, stream>>>(gbLo, gbHi, cnt, adj, b2,
                                                        (const void*)h1, W3, nullptr,
                                                        gaLo, gaHi, N);
    // --- final: out = agg(ga) + b3 ---
    agg_kernel<<<halfBlocks, 128, 0, stream>>>(gaLo, gaHi, cnt, adj, b3, out, N);
}

// Round 10
// 178.380 us; speedup vs baseline: 1.3600x; 1.0449x over previous
//
#include <hip/hip_runtime.h>
#include <hip/hip_bf16.h>

// ---------------------------------------------------------------------------
// GCN 3-layer, N=50000, E=800000, D=64, fp32 in/out.
// R23 = revert to R19 (best measured: 182.44us), declared terminal.
// ROOFLINE ACCOUNTING: dur 182.4 = 44us harness ws-poison fill (in timed
// region, untouchable) + ~138us pipeline. The three gather phases (~85-90us)
// move ~158MB each (fetch + dirty-poison-eviction writebacks, per R20
// counters: agg FETCH 84.5MB, WRITE 74MB vs 12.8MB logical output) in ~28us
// = ~5.7TB/s ~= 90% of the 6.3TB/s achievable ceiling — BANDWIDTH-SATURATED.
// Falsified levers (R14-R22): +concurrency (+4.5%), chain-cut (+2.7%),
// row dbuf (null), 19MB stream cut (null), (256,8) occupancy push (-33%,
// VGPR=32 broke MLP), lo/hi list split (-5%), planar L2-windowing x2
// (null/neg: blocks desync, no chip-wide phase), persistent mega-kernel
// (-5x: spin-barrier herd). fp8 table would halve gather bytes but blows
// the 0.035 absmax budget; graph clustering isn't computable in-budget.
// Structure: bucket adjacency CAP=64 XCD-partitioned fill (R3/R4), bf16
// g-table (R6), MFMA 16x16x32 gemm (R8), agg(l)+gemm(l+1) fusion through
// LDS A-frags (R13), 32-node blocks (R14), index-prefetch gather + stage_W
// after Phase A + dinv via LDS (R15), bf16 h1 + LDS-staged coalesced
// stores (R19).
// ---------------------------------------------------------------------------

#define CAP 64
#define EDGE_CHUNK 1024

typedef __attribute__((ext_vector_type(8))) short bf16x8;
typedef __attribute__((ext_vector_type(4))) float f32x4;

// --- pack two fp32 -> bf16x2 (RNE) ----------------------------------------
__device__ inline unsigned pack_bf16(float a, float b) {
    union { float f; unsigned i; } ua, ub;
    ua.f = a; ub.f = b;
    unsigned x = (ua.i + 0x7fffu + ((ua.i >> 16) & 1u)) >> 16;
    unsigned y = (ub.i + 0x7fffu + ((ub.i >> 16) & 1u)) >> 16;
    return x | (y << 16);
}
__device__ inline unsigned short to_bf16(float a) {
    union { float f; unsigned i; } u; u.f = a;
    return (unsigned short)((u.i + 0x7fffu + ((u.i >> 16) & 1u)) >> 16);
}
// --- accumulate bf16x2 (packed uint) into two floats ----------------------
__device__ inline void acc_bf16x2(unsigned u, float& a, float& b) {
    union { unsigned i; float f; } lo, hi;
    lo.i = u << 16;
    hi.i = u & 0xffff0000u;
    a += lo.f; b += hi.f;
}

// --- 8-lane/node uint4 row gather with index prefetch (R15 form) ----------
__device__ inline void gather_rows(const unsigned short* __restrict__ g,
                                   const int* __restrict__ lst, int deg, int c8,
                                   float& a0, float& a1, float& a2, float& a3,
                                   float& a4, float& a5, float& a6, float& a7) {
    int nfull = deg >> 3;              // full 8-batches
    int4 ja, jb;
    if (nfull > 0) { ja = *(const int4*)&lst[0]; jb = *(const int4*)&lst[4]; }
    for (int b = 0; b < nfull; b++) {
        int4 na = ja, nb = jb;         // prefetch next batch's indices
        if (b + 1 < nfull) {
            na = *(const int4*)&lst[(b + 1) * 8];
            nb = *(const int4*)&lst[(b + 1) * 8 + 4];
        }
        uint4 w0 = *(const uint4*)&g[(size_t)ja.x * 64 + c8];
        uint4 w1 = *(const uint4*)&g[(size_t)ja.y * 64 + c8];
        uint4 w2 = *(const uint4*)&g[(size_t)ja.z * 64 + c8];
        uint4 w3 = *(const uint4*)&g[(size_t)ja.w * 64 + c8];
        uint4 w4 = *(const uint4*)&g[(size_t)jb.x * 64 + c8];
        uint4 w5 = *(const uint4*)&g[(size_t)jb.y * 64 + c8];
        uint4 w6 = *(const uint4*)&g[(size_t)jb.z * 64 + c8];
        uint4 w7 = *(const uint4*)&g[(size_t)jb.w * 64 + c8];
        acc_bf16x2(w0.x, a0, a1); acc_bf16x2(w0.y, a2, a3);
        acc_bf16x2(w0.z, a4, a5); acc_bf16x2(w0.w, a6, a7);
        acc_bf16x2(w1.x, a0, a1); acc_bf16x2(w1.y, a2, a3);
        acc_bf16x2(w1.z, a4, a5); acc_bf16x2(w1.w, a6, a7);
        acc_bf16x2(w2.x, a0, a1); acc_bf16x2(w2.y, a2, a3);
        acc_bf16x2(w2.z, a4, a5); acc_bf16x2(w2.w, a6, a7);
        acc_bf16x2(w3.x, a0, a1); acc_bf16x2(w3.y, a2, a3);
        acc_bf16x2(w3.z, a4, a5); acc_bf16x2(w3.w, a6, a7);
        acc_bf16x2(w4.x, a0, a1); acc_bf16x2(w4.y, a2, a3);
        acc_bf16x2(w4.z, a4, a5); acc_bf16x2(w4.w, a6, a7);
        acc_bf16x2(w5.x, a0, a1); acc_bf16x2(w5.y, a2, a3);
        acc_bf16x2(w5.z, a4, a5); acc_bf16x2(w5.w, a6, a7);
        acc_bf16x2(w6.x, a0, a1); acc_bf16x2(w6.y, a2, a3);
        acc_bf16x2(w6.z, a4, a5); acc_bf16x2(w6.w, a6, a7);
        acc_bf16x2(w7.x, a0, a1); acc_bf16x2(w7.y, a2, a3);
        acc_bf16x2(w7.z, a4, a5); acc_bf16x2(w7.w, a6, a7);
        ja = na; jb = nb;
    }
    int k = nfull * 8;
    if (k + 4 <= deg) {
        int4 j4 = *(const int4*)&lst[k];
        uint4 w0 = *(const uint4*)&g[(size_t)j4.x * 64 + c8];
        uint4 w1 = *(const uint4*)&g[(size_t)j4.y * 64 + c8];
        uint4 w2 = *(const uint4*)&g[(size_t)j4.z * 64 + c8];
        uint4 w3 = *(const uint4*)&g[(size_t)j4.w * 64 + c8];
        acc_bf16x2(w0.x, a0, a1); acc_bf16x2(w0.y, a2, a3);
        acc_bf16x2(w0.z, a4, a5); acc_bf16x2(w0.w, a6, a7);
        acc_bf16x2(w1.x, a0, a1); acc_bf16x2(w1.y, a2, a3);
        acc_bf16x2(w1.z, a4, a5); acc_bf16x2(w1.w, a6, a7);
        acc_bf16x2(w2.x, a0, a1); acc_bf16x2(w2.y, a2, a3);
        acc_bf16x2(w2.z, a4, a5); acc_bf16x2(w2.w, a6, a7);
        acc_bf16x2(w3.x, a0, a1); acc_bf16x2(w3.y, a2, a3);
        acc_bf16x2(w3.z, a4, a5); acc_bf16x2(w3.w, a6, a7);
        k += 4;
    }
    for (; k < deg; k++) {
        uint4 v = *(const uint4*)&g[(size_t)lst[k] * 64 + c8];
        acc_bf16x2(v.x, a0, a1); acc_bf16x2(v.y, a2, a3);
        acc_bf16x2(v.z, a4, a5); acc_bf16x2(v.w, a6, a7);
    }
}

// --- fused count+place: slot = atomicAdd(cnt), XCD-partitioned by dst -----
__global__ void fill_kernel(const int* __restrict__ src, const int* __restrict__ dst,
                            int* __restrict__ cnt, int* __restrict__ adj,
                            int E, int npc) {
    int cls = blockIdx.x & 7;          // -> XCD (round-robin heuristic)
    int base = (blockIdx.x >> 3) * EDGE_CHUNK;
    int end = min(base + EDGE_CHUNK, E);
    int lo = cls * npc, hi = lo + npc;
    for (int e = base + threadIdx.x; e < end; e += blockDim.x) {
        int d = dst[e];
        if (d >= lo && d < hi) {
            int p = atomicAdd(&cnt[d], 1);
            adj[(size_t)d * CAP + p] = src[e];
        }
    }
}

// --- stage W (fp32 64x64) into B-fragment order (bf16) in LDS -------------
__device__ inline void stage_W(const float* __restrict__ W, unsigned short* Wb, int t) {
#pragma unroll
    for (int e0 = 0; e0 < 2; e0++) {
        int e = t + e0 * 256;          // frag index 0..511
        int sc = e >> 6;               // s*4 + c
        int l  = e & 63;               // target lane
        int s = sc >> 2, c = sc & 3;
        int nn = c * 16 + (l & 15);
        int kb = s * 32 + (l >> 4) * 8;
        const float* wp = &W[(size_t)kb * 64 + nn];
        unsigned q0 = pack_bf16(wp[0 * 64], wp[1 * 64]);
        unsigned q1 = pack_bf16(wp[2 * 64], wp[3 * 64]);
        unsigned q2 = pack_bf16(wp[4 * 64], wp[5 * 64]);
        unsigned q3 = pack_bf16(wp[6 * 64], wp[7 * 64]);
        *(uint4*)&Wb[e * 8] = make_uint4(q0, q1, q2, q3);
    }
}

// --- g(bf16) = dinv ⊙ (in @ W) via MFMA; 64 rows/block (layer 1 only) -----
// Output staged through Wb-as-Ofrag (free after MFMA) for coalesced stores.
__global__ __launch_bounds__(256, 4) void gemm_kernel(const float* __restrict__ in,
                                                      const float* __restrict__ W,
                                                      const int* __restrict__ cnt,
                                                      unsigned short* __restrict__ g, int n) {
    __shared__ unsigned short Wb[512 * 8];     // B-frags, then out-tile alias
    int t = threadIdx.x;
    stage_W(W, Wb, t);

    int wv = t >> 6;
    int lane = t & 63;
    int quad = lane >> 4;
    int m16 = lane & 15;

    int rowA = blockIdx.x * 64 + wv * 16 + m16;
    union { bf16x8 v; uint4 u; } a0, a1;
    {
        float4 f0 = make_float4(0, 0, 0, 0), f1 = f0, f2 = f0, f3 = f0;
        if (rowA < n) {
            const float* rp = &in[(size_t)rowA * 64];
            f0 = *(const float4*)&rp[quad * 8];
            f1 = *(const float4*)&rp[quad * 8 + 4];
            f2 = *(const float4*)&rp[32 + quad * 8];
            f3 = *(const float4*)&rp[32 + quad * 8 + 4];
        }
        a0.u = make_uint4(pack_bf16(f0.x, f0.y), pack_bf16(f0.z, f0.w),
                          pack_bf16(f1.x, f1.y), pack_bf16(f1.z, f1.w));
        a1.u = make_uint4(pack_bf16(f2.x, f2.y), pack_bf16(f2.z, f2.w),
                          pack_bf16(f3.x, f3.y), pack_bf16(f3.z, f3.w));
    }
    __syncthreads();

    f32x4 acc[4];
#pragma unroll
    for (int c = 0; c < 4; c++) {
        bf16x8 b0 = *(const bf16x8*)&Wb[((size_t)(0 * 4 + c) * 64 + lane) * 8];
        bf16x8 b1 = *(const bf16x8*)&Wb[((size_t)(1 * 4 + c) * 64 + lane) * 8];
        f32x4 z = {0.f, 0.f, 0.f, 0.f};
        z = __builtin_amdgcn_mfma_f32_16x16x32_bf16(a0.v, b0, z, 0, 0, 0);
        z = __builtin_amdgcn_mfma_f32_16x16x32_bf16(a1.v, b1, z, 0, 0, 0);
        acc[c] = z;
    }

    int lrow = wv * 16 + quad * 4;            // local row base 0..63
    float dv[4];
#pragma unroll
    for (int r = 0; r < 4; r++) {
        int row = blockIdx.x * 64 + lrow + r;
        dv[r] = (row < n) ? rsqrtf((float)(cnt[row] + 1)) : 0.f;
    }
    __syncthreads();                          // Wb B-frag reads all done
    unsigned short* Ofrag = Wb;               // 64x64 ushort = 8KB alias
#pragma unroll
    for (int c = 0; c < 4; c++) {
#pragma unroll
        for (int r = 0; r < 4; r++)
            Ofrag[(size_t)(lrow + r) * 64 + c * 16 + m16] = to_bf16(acc[c][r] * dv[r]);
    }
    __syncthreads();
#pragma unroll
    for (int it = 0; it < 2; it++) {
        int unit = t + it * 256;              // 512 units: 64 rows x 8 chunks
        int row = unit >> 3, chv = unit & 7;
        int grow = blockIdx.x * 64 + row;
        if (grow < n)
            *(uint4*)&g[(size_t)grow * 64 + chv * 8] =
                *(const uint4*)&Ofrag[(size_t)row * 64 + chv * 8];
    }
}

// --- fused agg(l) + gemm(l+1); 32 nodes/block (R14/R15/R19) ---------------
// Phase A: R15 uint4 gather (8 lanes/node); h = relu(dinv*sum+bias)+res;
// h written bf16 (WRITE_H); deposit h into A-frag LDS + dinv into LDS.
// Phase B: MFMA, then out-tile staged back into Afrag for coalesced stores.
template <int WRITE_H, int RES_BF16>
__global__ __launch_bounds__(256, 4) void aggemm_kernel(
        const unsigned short* __restrict__ g_in,
        const int* __restrict__ cnt,
        const int* __restrict__ adj,
        const float* __restrict__ bias,
        const void* __restrict__ res_p,
        const float* __restrict__ W,
        unsigned short* __restrict__ h_out,   // bf16 h (if WRITE_H)
        unsigned short* __restrict__ g_out,
        int n) {
    __shared__ unsigned short Wb[512 * 8];     // 8 KB B-frags
    __shared__ unsigned short Afrag[2048];     // 4 KB A-frags, then out-tile
    __shared__ float dsh[32];                  // per-node dinv for Phase B
    int t = threadIdx.x;

    // ---- Phase A: aggregate 32 nodes, 8 lanes/node, uint4 ----
    int r  = t >> 3;                   // node-in-block 0..31
    int lg = t & 7;
    const int c8 = lg * 8;
    int i = blockIdx.x * 32 + r;
    float v0 = 0.f, v1 = 0.f, v2 = 0.f, v3 = 0.f;
    float v4 = 0.f, v5 = 0.f, v6 = 0.f, v7 = 0.f;
    float dvv = 0.f;
    if (i < n) {
        int deg = cnt[i];
        const int* lst = adj + (size_t)i * CAP;
        float r0 = 0.f, r1 = 0.f, r2 = 0.f, r3 = 0.f;
        float r4 = 0.f, r5 = 0.f, r6 = 0.f, r7 = 0.f;
        if (RES_BF16) {                // hoisted residual load (bf16 h1)
            const unsigned short* rp = (const unsigned short*)res_p;
            uint4 rv = *(const uint4*)&rp[(size_t)i * 64 + c8];
            acc_bf16x2(rv.x, r0, r1); acc_bf16x2(rv.y, r2, r3);
            acc_bf16x2(rv.z, r4, r5); acc_bf16x2(rv.w, r6, r7);
        } else {                       // fp32 residual (x)
            const float* rp = (const float*)res_p;
            float4 q0 = *(const float4*)&rp[(size_t)i * 64 + c8];
            float4 q1 = *(const float4*)&rp[(size_t)i * 64 + c8 + 4];
            r0 = q0.x; r1 = q0.y; r2 = q0.z; r3 = q0.w;
            r4 = q1.x; r5 = q1.y; r6 = q1.z; r7 = q1.w;
        }
        float a0 = 0.f, a1 = 0.f, a2 = 0.f, a3 = 0.f;
        float a4 = 0.f, a5 = 0.f, a6 = 0.f, a7 = 0.f;
        {   // self loop
            uint4 v = *(const uint4*)&g_in[(size_t)i * 64 + c8];
            acc_bf16x2(v.x, a0, a1); acc_bf16x2(v.y, a2, a3);
            acc_bf16x2(v.z, a4, a5); acc_bf16x2(v.w, a6, a7);
        }
        gather_rows(g_in, lst, deg, c8, a0, a1, a2, a3, a4, a5, a6, a7);
        dvv = rsqrtf((float)(deg + 1));
        float4 b0 = *(const float4*)&bias[c8];
        float4 b1 = *(const float4*)&bias[c8 + 4];
        v0 = fmaxf(dvv * a0 + b0.x, 0.f) + r0;
        v1 = fmaxf(dvv * a1 + b0.y, 0.f) + r1;
        v2 = fmaxf(dvv * a2 + b0.z, 0.f) + r2;
        v3 = fmaxf(dvv * a3 + b0.w, 0.f) + r3;
        v4 = fmaxf(dvv * a4 + b1.x, 0.f) + r4;
        v5 = fmaxf(dvv * a5 + b1.y, 0.f) + r5;
        v6 = fmaxf(dvv * a6 + b1.z, 0.f) + r6;
        v7 = fmaxf(dvv * a7 + b1.w, 0.f) + r7;
    }
    // pack h row chunk once: reused for h_out write and A-frag deposit
    uint4 pk;
    pk.x = pack_bf16(v0, v1);
    pk.y = pack_bf16(v2, v3);
    pk.z = pack_bf16(v4, v5);
    pk.w = pack_bf16(v6, v7);
    if (WRITE_H && i < n)
        *(uint4*)&h_out[(size_t)i * 64 + c8] = pk;
    // stage W after the gather (R15): latency hides under other waves' A.
    stage_W(W, Wb, t);
    {
        int sA = r >> 4, mA = r & 15;
        *(uint4*)&Afrag[((size_t)(sA * 8 + lg) * 16 + mA) * 8] = pk;
        if (lg == 0) dsh[r] = dvv;
    }
    __syncthreads();

    // ---- Phase B: MFMA gemm on the 32-row tile ----
    int wv = t >> 6;
    int lane = t & 63;
    int quad = lane >> 4;
    int m16 = lane & 15;
    int sB = wv & 1;                   // row sub-tile 0..1
    int ch = wv >> 1;                  // col half 0..1
    bf16x8 af0 = *(const bf16x8*)&Afrag[((size_t)(sB * 8 + quad) * 16 + m16) * 8];
    bf16x8 af1 = *(const bf16x8*)&Afrag[((size_t)(sB * 8 + 4 + quad) * 16 + m16) * 8];
    int lrow = sB * 16 + quad * 4;     // local row 0..31
    float dv2[4];
#pragma unroll
    for (int rr = 0; rr < 4; rr++)
        dv2[rr] = dsh[lrow + rr];
    __syncthreads();                   // all A-frag reads done before overwrite
    f32x4 acc[2];
#pragma unroll
    for (int c2 = 0; c2 < 2; c2++) {
        int c = ch * 2 + c2;
        bf16x8 b0 = *(const bf16x8*)&Wb[((size_t)(0 * 4 + c) * 64 + lane) * 8];
        bf16x8 b1 = *(const bf16x8*)&Wb[((size_t)(1 * 4 + c) * 64 + lane) * 8];
        f32x4 z = {0.f, 0.f, 0.f, 0.f};
        z = __builtin_amdgcn_mfma_f32_16x16x32_bf16(af0, b0, z, 0, 0, 0);
        z = __builtin_amdgcn_mfma_f32_16x16x32_bf16(af1, b1, z, 0, 0, 0);
        acc[c2] = z;
    }
    // stage out-tile into Afrag [32][64] for coalesced stores
#pragma unroll
    for (int c2 = 0; c2 < 2; c2++) {
        int c = ch * 2 + c2;
#pragma unroll
        for (int rr = 0; rr < 4; rr++)
            Afrag[(size_t)(lrow + rr) * 64 + c * 16 + m16] = to_bf16(acc[c2][rr] * dv2[rr]);
    }
    __syncthreads();
    {
        int orow = blockIdx.x * 32 + r;
        if (orow < n)
            *(uint4*)&g_out[(size_t)orow * 64 + c8] =
                *(const uint4*)&Afrag[(size_t)r * 64 + c8];
    }
}

// --- final aggregation: 8 lanes/node uint4 gather -------------------------
__global__ __launch_bounds__(256, 4) void agg_kernel(const unsigned short* __restrict__ g,
                                                     const int* __restrict__ cnt,
                                                     const int* __restrict__ adj,
                                                     const float* __restrict__ bias,
                                                     float* __restrict__ out, int n) {
    int t = threadIdx.x;
    int lg = t & 7;
    int i = blockIdx.x * 32 + (t >> 3);
    if (i >= n) return;
    int deg = cnt[i];
    const int* lst = adj + (size_t)i * CAP;
    const int c8 = lg * 8;
    size_t rowoff = (size_t)i * 64 + c8;
    float a0 = 0.f, a1 = 0.f, a2 = 0.f, a3 = 0.f;
    float a4 = 0.f, a5 = 0.f, a6 = 0.f, a7 = 0.f;
    {   // self loop
        uint4 v = *(const uint4*)&g[(size_t)i * 64 + c8];
        acc_bf16x2(v.x, a0, a1); acc_bf16x2(v.y, a2, a3);
        acc_bf16x2(v.z, a4, a5); acc_bf16x2(v.w, a6, a7);
    }
    gather_rows(g, lst, deg, c8, a0, a1, a2, a3, a4, a5, a6, a7);
    float dv = rsqrtf((float)(deg + 1));
    float4 b0 = *(const float4*)&bias[c8];
    float4 b1 = *(const float4*)&bias[c8 + 4];
    float4 o0, o1;
    o0.x = dv * a0 + b0.x; o0.y = dv * a1 + b0.y;
    o0.z = dv * a2 + b0.z; o0.w = dv * a3 + b0.w;
    o1.x = dv * a4 + b1.x; o1.y = dv * a5 + b1.y;
    o1.z = dv * a6 + b1.z; o1.w = dv * a7 + b1.w;
    *(float4*)&out[rowoff] = o0;
    *(float4*)&out[rowoff + 4] = o1;
}

extern "C" void kernel_launch(void* const* d_in, const int* in_sizes, int n_in,
                              void* d_out, int out_size, void* d_ws, size_t ws_size,
                              hipStream_t stream) {
    const float* x  = (const float*)d_in[0];
    const int*   ei = (const int*)d_in[1];
    const float* W1 = (const float*)d_in[2];
    const float* b1 = (const float*)d_in[3];
    const float* W2 = (const float*)d_in[4];
    const float* b2 = (const float*)d_in[5];
    const float* W3 = (const float*)d_in[6];
    const float* b3 = (const float*)d_in[7];
    float* out = (float*)d_out;

    const int N = in_sizes[0] / 64;
    const int E = in_sizes[1] / 2;
    const int* src = ei;
    const int* dst = ei + E;
    const int npc = (N + 7) / 8;
    const int nEdgeChunks = (E + EDGE_CHUNK - 1) / EDGE_CHUNK;

    // workspace layout
    char* p = (char*)d_ws;
    const int Na = ((N + 63) / 64) * 64;
    int*            cnt = (int*)p;            p += (size_t)Na * 4;
    int*            adj = (int*)p;            p += ((size_t)N + 1) * CAP * 4;
    unsigned short* ga  = (unsigned short*)p; p += (size_t)N * 64 * 2;
    unsigned short* gb  = (unsigned short*)p; p += (size_t)N * 64 * 2;
    unsigned short* h1  = (unsigned short*)p; p += (size_t)N * 64 * 2;   // bf16

    const int tileBlocks = (N + 63) / 64;   // gemm (64-row MFMA tiles)
    const int halfBlocks = (N + 31) / 32;   // aggemm + final agg (32 nodes)

    // --- bucket adjacency build (ws re-poisoned every call) ---
    hipMemsetAsync(cnt, 0, (size_t)N * 4, stream);
    fill_kernel<<<nEdgeChunks * 8, 256, 0, stream>>>(src, dst, cnt, adj, E, npc);

    // --- layer 1 gemm: ga = dinv ⊙ (x@W1) ---
    gemm_kernel<<<tileBlocks, 256, 0, stream>>>(x, W1, cnt, ga, N);
    // --- fused: h1 = relu(agg(ga))+x (bf16) ; gb = dinv ⊙ (h1@W2) ---
    aggemm_kernel<1, 0><<<halfBlocks, 256, 0, stream>>>(ga, cnt, adj, b1, (const void*)x,
                                                        W2, h1, gb, N);
    // --- fused: h2 = relu(agg(gb))+h1 ; ga = dinv ⊙ (h2@W3) ---
    aggemm_kernel<0, 1><<<halfBlocks, 256, 0, stream>>>(gb, cnt, adj, b2, (const void*)h1,
                                                        W3, nullptr, ga, N);
    // --- final: out = agg(ga) + b3 ---
    agg_kernel<<<halfBlocks, 256, 0, stream>>>(ga, cnt, adj, b3, out, N);
}